// Round 18
// baseline (923.308 us; speedup 1.0000x reference)
//
#include <hip/hip_runtime.h>
#include <hip/hip_bf16.h>
#include <cstdint>

// AttnLayerBU round 18: r17 + LDS overlay for 3 blocks/CU in mega (52224 B:
// Qs/Ks/K4t/scratch overlay the dead Xs region; +2 barriers), aux attn bodies
// use per-chunk-Q (r10-verified, <=44160 B), cvt & epilogue launches merged.

#define DIM 256
#define NH 8
#define HD 32

static constexpr float SCALE = 0.17677669529663687f; // 32^-0.5

typedef __bf16 bf16x8 __attribute__((ext_vector_type(8)));
typedef __bf16 bf16x4 __attribute__((ext_vector_type(4)));
typedef float  f32x4  __attribute__((ext_vector_type(4)));

__device__ __forceinline__ float dot4(const float4 a, const float4 b) {
    return a.x * b.x + a.y * b.y + a.z * b.z + a.w * b.w;
}

// ---------------------------------------------------------------------------
// merged weight converter: 5 ranges in one launch
// ---------------------------------------------------------------------------
__device__ __forceinline__ void cvt_range(const float* __restrict__ s,
                                          __bf16* __restrict__ d, int lb, int n) {
    int i = (lb * 256 + (int)threadIdx.x) * 4;
    if (i < n) {
        float4 v = *(const float4*)(s + i);
        d[i + 0] = (__bf16)v.x; d[i + 1] = (__bf16)v.y;
        d[i + 2] = (__bf16)v.z; d[i + 3] = (__bf16)v.w;
    }
}

__global__ __launch_bounds__(256) void cvt_all(
    const float* __restrict__ w_in, const float* __restrict__ w_out,
    __bf16* __restrict__ W1b, __bf16* __restrict__ W4kvb,
    __bf16* __restrict__ Wo1b, __bf16* __restrict__ Wv0b,
    __bf16* __restrict__ Wo0b)
{
    const size_t WI = 768 * 256, WO = 256 * 256;
    const int bid = blockIdx.x;
    if (bid < 192)       cvt_range(w_in + 1 * WI, W1b, bid, 768 * 256);
    else if (bid < 320)  cvt_range(w_in + 4 * WI + 256 * 256, W4kvb, bid - 192, 512 * 256);
    else if (bid < 384)  cvt_range(w_out + 1 * WO, Wo1b, bid - 320, 256 * 256);
    else if (bid < 448)  cvt_range(w_in + 512 * 256, Wv0b, bid - 384, 256 * 256);
    else                 cvt_range(w_out, Wo0b, bid - 448, 256 * 256);
}

// ---------------------------------------------------------------------------
// mega2 body. LDS (52224 B):
//   region A [0,33792): Xs[64][264] during staging; after af-load barrier:
//     Qs[64][72]@0 (Pw 4x[16][72] overlays Qs after pre-PV barrier),
//     Ks[64][72]@9216, K4t[64][72]@18432, scratch f32 @27648 (2304)
//   Vt[64][72]@33792   V4t[64][72]@43008
// ---------------------------------------------------------------------------
__device__ void mega2_body(int g,
    const float* __restrict__ X, const float* __restrict__ inner,
    const __bf16* __restrict__ W1b, const float* __restrict__ Bi1,
    const __bf16* __restrict__ W4kvb, const float* __restrict__ W4q,
    const float* __restrict__ Bi4, __bf16* __restrict__ O1,
    float* __restrict__ Oc, char* __restrict__ smem)
{
    const int xcd  = g & 7;
    const int idx  = g >> 3;               // 0..1023
    const int b    = xcd * 256 + (idx >> 2);
    const int hg   = idx & 3;              // head-pair: heads 2hg, 2hg+1
    const int tid  = threadIdx.x;
    const int wid  = tid >> 6;             // 0..3
    const int lane = tid & 63;
    const int lr   = lane & 15;
    const int lk   = (lane >> 4) * 8;
    const int prow = (lane >> 4) * 4;

    __bf16* Xs  = (__bf16*)smem;                    // [64][264] (staging)
    __bf16* Qs  = (__bf16*)smem;                    // [64][72] overlay
    __bf16* Pw  = (__bf16*)(smem + wid * 2304);     // overlay on Qs (post-PV-barrier)
    __bf16* Ks  = (__bf16*)(smem + 9216);           // [64][72]
    __bf16* K4t = (__bf16*)(smem + 18432);          // [64col][72]
    float* qpart = (float*)(smem + 27648);          // [4][64]
    float* qv    = qpart + 256;                     // [64]
    float* psm   = qv + 64;                         // [2][64]
    float* opart = psm + 128;                       // [2][64]
    __bf16* Vt  = (__bf16*)(smem + 33792);          // [64 d][72 tok]
    __bf16* V4t = (__bf16*)(smem + 43008);          // [64col][72]

    // ---- stage X tile (fp32 -> bf16) into Xs, coalesced ----
    {
        const float* xb = X + (size_t)b * 64 * DIM;
#pragma unroll
        for (int it = 0; it < 16; ++it) {
            const int e4 = it * 1024 + tid * 4;
            const f32x4 v = __builtin_nontemporal_load((const f32x4*)(xb + e4));
            bf16x4 t4;
            t4[0] = (__bf16)v[0]; t4[1] = (__bf16)v[1];
            t4[2] = (__bf16)v[2]; t4[3] = (__bf16)v[3];
            const int row = e4 >> 8, col = e4 & 255;
            *(bf16x4*)(Xs + row * 264 + col) = t4;
        }
    }
    __syncthreads();                                 // b1: Xs ready

    // ---- load ALL A-fragments into registers: 4 row-groups x 8 k ----
    bf16x8 af[4][8];
#pragma unroll
    for (int tg = 0; tg < 4; ++tg)
#pragma unroll
        for (int kk = 0; kk < 8; ++kk)
            af[tg][kk] = *(const bf16x8*)(Xs + (size_t)(tg * 16 + lr) * 264 + kk * 32 + lk);
    __syncthreads();                                 // b2: Xs dead (overlay OK)

    // ---- projection: wave owns n-tiles wid*5..+4, A & B in regs, no barriers
    {
        auto wsrc = [&](int t) -> const __bf16* {
            if (t < 12) {
                const int sec = t >> 2, sub = t & 3;
                return W1b + (size_t)(sec * 256 + hg * 64 + sub * 16) * DIM;
            }
            const int u = t - 12, sec = u >> 2, sub = u & 3;
            return W4kvb + (size_t)(sec * 256 + hg * 64 + sub * 16) * DIM;
        };
        const size_t boff = (size_t)lr * DIM + lk;
        const int t0w = wid * 5;
        bf16x8 bw[8], bn[8];
        {
            const __bf16* p = wsrc(t0w) + boff;
#pragma unroll
            for (int kk = 0; kk < 8; ++kk) bw[kk] = *(const bf16x8*)(p + kk * 32);
        }
        for (int i = 0; i < 5; ++i) {
            const int t = t0w + i;
            if (i + 1 < 5) {
                const __bf16* p = wsrc(t + 1) + boff;
#pragma unroll
                for (int kk = 0; kk < 8; ++kk) bn[kk] = *(const bf16x8*)(p + kk * 32);
            }
            f32x4 acc0 = {0.f,0.f,0.f,0.f}, acc1 = {0.f,0.f,0.f,0.f};
            f32x4 acc2 = {0.f,0.f,0.f,0.f}, acc3 = {0.f,0.f,0.f,0.f};
#pragma unroll
            for (int kk = 0; kk < 8; ++kk) {
                acc0 = __builtin_amdgcn_mfma_f32_16x16x32_bf16(af[0][kk], bw[kk], acc0, 0, 0, 0);
                acc1 = __builtin_amdgcn_mfma_f32_16x16x32_bf16(af[1][kk], bw[kk], acc1, 0, 0, 0);
                acc2 = __builtin_amdgcn_mfma_f32_16x16x32_bf16(af[2][kk], bw[kk], acc2, 0, 0, 0);
                acc3 = __builtin_amdgcn_mfma_f32_16x16x32_bf16(af[3][kk], bw[kk], acc3, 0, 0, 0);
            }
            f32x4 accT[4] = { acc0, acc1, acc2, acc3 };
            const int sub = t & 3;
            const int col = sub * 16 + lr;
            if (t < 4) {                            // Q (scaled)
                const float bias = Bi1[hg * 64 + sub * 16 + lr];
#pragma unroll
                for (int tg = 0; tg < 4; ++tg)
#pragma unroll
                    for (int r = 0; r < 4; ++r)
                        Qs[(size_t)(tg * 16 + prow + r) * 72 + col] =
                            (__bf16)((accT[tg][r] + bias) * SCALE);
            } else if (t < 8) {                     // K
                const float bias = Bi1[256 + hg * 64 + sub * 16 + lr];
#pragma unroll
                for (int tg = 0; tg < 4; ++tg)
#pragma unroll
                    for (int r = 0; r < 4; ++r)
                        Ks[(size_t)(tg * 16 + prow + r) * 72 + col] =
                            (__bf16)(accT[tg][r] + bias);
            } else if (t < 12) {                    // V -> [d][tok]
                const float bias = Bi1[512 + hg * 64 + sub * 16 + lr];
#pragma unroll
                for (int tg = 0; tg < 4; ++tg) {
                    bf16x4 pv;
#pragma unroll
                    for (int r = 0; r < 4; ++r) pv[r] = (__bf16)(accT[tg][r] + bias);
                    *(bf16x4*)(Vt + (size_t)col * 72 + tg * 16 + prow) = pv;
                }
            } else if (t < 16) {                    // K4 -> [d][tok]
                const float bias = Bi4[256 + hg * 64 + sub * 16 + lr];
#pragma unroll
                for (int tg = 0; tg < 4; ++tg) {
                    bf16x4 pv;
#pragma unroll
                    for (int r = 0; r < 4; ++r) pv[r] = (__bf16)(accT[tg][r] + bias);
                    *(bf16x4*)(K4t + (size_t)col * 72 + tg * 16 + prow) = pv;
                }
            } else {                                // V4 -> [d][tok]
                const float bias = Bi4[512 + hg * 64 + sub * 16 + lr];
#pragma unroll
                for (int tg = 0; tg < 4; ++tg) {
                    bf16x4 pv;
#pragma unroll
                    for (int r = 0; r < 4; ++r) pv[r] = (__bf16)(accT[tg][r] + bias);
                    *(bf16x4*)(V4t + (size_t)col * 72 + tg * 16 + prow) = pv;
                }
            }
#pragma unroll
            for (int kk = 0; kk < 8; ++kk) bw[kk] = bn[kk];
        }
    }
    __syncthreads();                                 // b3: proj done

    // ---- inner_c q-projection partials ----
    {
        const int o = tid & 63, part = tid >> 6;
        const float4* wr = (const float4*)(W4q + (size_t)(hg * 64 + o) * DIM + part * 64);
        const float4* xr = (const float4*)(inner + (size_t)b * DIM + part * 64);
        float accq = 0.f;
#pragma unroll
        for (int k = 0; k < 16; ++k) accq += dot4(xr[k], wr[k]);
        qpart[part * 64 + o] = accq;
    }
    __syncthreads();                                 // b4

    if (tid < 64)
        qv[tid] = (qpart[tid] + qpart[64 + tid] + qpart[128 + tid] + qpart[192 + tid]
                   + Bi4[hg * 64 + tid]) * SCALE;

    // ---- leaf_s attention: wave = (head hh, q-half qh) ----
    const int hh = wid >> 1;
    const int qh = wid & 1;
    f32x4 s[2][4];
    {
        bf16x8 kb[4];
#pragma unroll
        for (int kt = 0; kt < 4; ++kt)
            kb[kt] = *(const bf16x8*)(Ks + (size_t)(kt * 16 + lr) * 72 + hh * 32 + lk);
#pragma unroll
        for (int q2 = 0; q2 < 2; ++q2) {
            const int qt = qh * 2 + q2;
            const bf16x8 qa = *(const bf16x8*)(Qs + (size_t)(qt * 16 + lr) * 72 + hh * 32 + lk);
#pragma unroll
            for (int kt = 0; kt < 4; ++kt) {
                f32x4 z = {0.f, 0.f, 0.f, 0.f};
                s[q2][kt] = __builtin_amdgcn_mfma_f32_16x16x32_bf16(qa, kb[kt], z, 0, 0, 0);
            }
        }
    }
#pragma unroll
    for (int q2 = 0; q2 < 2; ++q2) {
#pragma unroll
        for (int r = 0; r < 4; ++r) {
            float m = fmaxf(fmaxf(s[q2][0][r], s[q2][1][r]), fmaxf(s[q2][2][r], s[q2][3][r]));
#pragma unroll
            for (int off = 1; off < 16; off <<= 1) m = fmaxf(m, __shfl_xor(m, off));
            const float p0 = __expf(s[q2][0][r] - m), p1 = __expf(s[q2][1][r] - m);
            const float p2 = __expf(s[q2][2][r] - m), p3 = __expf(s[q2][3][r] - m);
            float t = p0 + p1 + p2 + p3;
#pragma unroll
            for (int off = 1; off < 16; off <<= 1) t += __shfl_xor(t, off);
            const float inv = 1.0f / t;
            s[q2][0][r] = p0 * inv; s[q2][1][r] = p1 * inv;
            s[q2][2][r] = p2 * inv; s[q2][3][r] = p3 * inv;
        }
    }
    bf16x8 vb[2][2];
#pragma unroll
    for (int dt = 0; dt < 2; ++dt)
#pragma unroll
        for (int ks = 0; ks < 2; ++ks)
            vb[dt][ks] = *(const bf16x8*)(Vt + (size_t)(hh * 32 + dt * 16 + lr) * 72 + ks * 32 + lk);
    __syncthreads();                                 // b5: Qs reads done (Pw overlay safe)

    {
#pragma unroll
        for (int q2 = 0; q2 < 2; ++q2) {
            const int qt = qh * 2 + q2;
#pragma unroll
            for (int kt = 0; kt < 4; ++kt)
#pragma unroll
                for (int r = 0; r < 4; ++r)
                    Pw[(size_t)(prow + r) * 72 + kt * 16 + lr] = (__bf16)s[q2][kt][r];
            bf16x8 pa[2];
#pragma unroll
            for (int ks = 0; ks < 2; ++ks)
                pa[ks] = *(const bf16x8*)(Pw + (size_t)lr * 72 + ks * 32 + lk);
#pragma unroll
            for (int dt = 0; dt < 2; ++dt) {
                f32x4 o = {0.f, 0.f, 0.f, 0.f};
#pragma unroll
                for (int ks = 0; ks < 2; ++ks)
                    o = __builtin_amdgcn_mfma_f32_16x16x32_bf16(pa[ks], vb[dt][ks], o, 0, 0, 0);
                const int colO = (hg * 2 + hh) * 32 + dt * 16 + lr;
#pragma unroll
                for (int r = 0; r < 4; ++r)
                    __builtin_nontemporal_store((__bf16)o[r],
                        &O1[((size_t)b * 64 + qt * 16 + prow + r) * DIM + colO]);
            }
        }
    }
    __syncthreads();                                 // b6: PV done, qv ready

    if (wid < 2) {
        const int j = lane;
        float sv = 0.f;
#pragma unroll
        for (int d = 0; d < 32; ++d)
            sv += qv[wid * 32 + d] * (float)K4t[(size_t)(wid * 32 + d) * 72 + j];
        float m = sv;
#pragma unroll
        for (int off = 1; off < 64; off <<= 1) m = fmaxf(m, __shfl_xor(m, off));
        const float p = __expf(sv - m);
        float t = p;
#pragma unroll
        for (int off = 1; off < 64; off <<= 1) t += __shfl_xor(t, off);
        psm[wid * 64 + j] = p / t;
    }
    __syncthreads();

    if (tid < 128) {
        const int o = tid & 63, hf = tid >> 6;
        const int ho = o >> 5;
        float acc2 = 0.f;
#pragma unroll
        for (int j = 0; j < 32; ++j)
            acc2 += psm[ho * 64 + hf * 32 + j] * (float)V4t[(size_t)o * 72 + hf * 32 + j];
        opart[hf * 64 + o] = acc2;
    }
    __syncthreads();
    if (tid < 64)
        Oc[(size_t)b * DIM + hg * 64 + tid] = opart[tid] + opart[64 + tid];
}

// ---------------------------------------------------------------------------
// leafp MFMA 2-stage (r12 verbatim; LDS 50688 <= 52224)
// ---------------------------------------------------------------------------
__device__ void leafp_mfma_body(int bid, const float* __restrict__ inner,
    const __bf16* __restrict__ Wv0b, const __bf16* __restrict__ Wo0b,
    const float* __restrict__ b_in0, const float* __restrict__ b_out0,
    float* __restrict__ tP, char* __restrict__ smem)
{
    __bf16* tV = (__bf16*)smem;             // [64][264]
    __bf16* Bs = (__bf16*)(smem + 33792);   // [2][16][264]
    const int tid  = threadIdx.x;
    const int wid  = tid >> 6;
    const int lane = tid & 63;
    const int lr   = lane & 15;
    const int lk   = (lane >> 4) * 8;
    const int prow = (lane >> 4) * 4;
    const int tok0 = wid * 16 + prow;
    const int srow = tid >> 5;
    const int scol = (tid & 31) * 8;

    bf16x8 a[8];
    {
        const float* xrow = inner + ((size_t)bid * 64 + wid * 16 + lr) * DIM + lk;
#pragma unroll
        for (int k = 0; k < 8; ++k) {
            float4 v0 = *(const float4*)(xrow + k * 32);
            float4 v1 = *(const float4*)(xrow + k * 32 + 4);
            bf16x8 t;
            t[0] = (__bf16)v0.x; t[1] = (__bf16)v0.y; t[2] = (__bf16)v0.z; t[3] = (__bf16)v0.w;
            t[4] = (__bf16)v1.x; t[5] = (__bf16)v1.y; t[6] = (__bf16)v1.z; t[7] = (__bf16)v1.w;
            a[k] = t;
        }
    }

    {
        bf16x8 g0 = *(const bf16x8*)(Wv0b + (size_t)srow * DIM + scol);
        bf16x8 g1 = *(const bf16x8*)(Wv0b + (size_t)(8 + srow) * DIM + scol);
        *(bf16x8*)(Bs + srow * 264 + scol) = g0;
        *(bf16x8*)(Bs + (8 + srow) * 264 + scol) = g1;
    }
    __syncthreads();
    for (int t = 0; t < 16; ++t) {
        const int cur = t & 1;
        const __bf16* Bc = Bs + cur * 4224;
        bf16x8 g0, g1;
        if (t + 1 < 16) {
            const __bf16* p = Wv0b + (size_t)((t + 1) * 16) * DIM;
            g0 = *(const bf16x8*)(p + (size_t)srow * DIM + scol);
            g1 = *(const bf16x8*)(p + (size_t)(8 + srow) * DIM + scol);
        }
        f32x4 acc = {0.f, 0.f, 0.f, 0.f};
#pragma unroll
        for (int k = 0; k < 8; ++k)
            acc = __builtin_amdgcn_mfma_f32_16x16x32_bf16(
                a[k], *(const bf16x8*)(Bc + lr * 264 + k * 32 + lk), acc, 0, 0, 0);
        const float bias = b_in0[512 + t * 16 + lr];
#pragma unroll
        for (int r = 0; r < 4; ++r)
            tV[(size_t)(tok0 + r) * 264 + t * 16 + lr] = (__bf16)(acc[r] + bias);
        if (t + 1 < 16) {
            __bf16* Bn = Bs + (cur ^ 1) * 4224;
            *(bf16x8*)(Bn + srow * 264 + scol) = g0;
            *(bf16x8*)(Bn + (8 + srow) * 264 + scol) = g1;
        }
        __syncthreads();
    }

    bf16x8 a2[8];
#pragma unroll
    for (int k = 0; k < 8; ++k)
        a2[k] = *(const bf16x8*)(tV + (size_t)(wid * 16 + lr) * 264 + k * 32 + lk);
    {
        bf16x8 g0 = *(const bf16x8*)(Wo0b + (size_t)srow * DIM + scol);
        bf16x8 g1 = *(const bf16x8*)(Wo0b + (size_t)(8 + srow) * DIM + scol);
        *(bf16x8*)(Bs + srow * 264 + scol) = g0;
        *(bf16x8*)(Bs + (8 + srow) * 264 + scol) = g1;
    }
    __syncthreads();
    for (int t = 0; t < 16; ++t) {
        const int cur = t & 1;
        const __bf16* Bc = Bs + cur * 4224;
        bf16x8 g0, g1;
        if (t + 1 < 16) {
            const __bf16* p = Wo0b + (size_t)((t + 1) * 16) * DIM;
            g0 = *(const bf16x8*)(p + (size_t)srow * DIM + scol);
            g1 = *(const bf16x8*)(p + (size_t)(8 + srow) * DIM + scol);
        }
        f32x4 acc = {0.f, 0.f, 0.f, 0.f};
#pragma unroll
        for (int k = 0; k < 8; ++k)
            acc = __builtin_amdgcn_mfma_f32_16x16x32_bf16(
                a2[k], *(const bf16x8*)(Bc + lr * 264 + k * 32 + lk), acc, 0, 0, 0);
        const float bo = b_out0[t * 16 + lr];
#pragma unroll
        for (int r = 0; r < 4; ++r)
            tP[((size_t)bid * 64 + wid * 16 + prow + r) * DIM + t * 16 + lr] = acc[r] + bo;
        if (t + 1 < 16) {
            __bf16* Bn = Bs + (cur ^ 1) * 4224;
            *(bf16x8*)(Bn + srow * 264 + scol) = g0;
            *(bf16x8*)(Bn + (8 + srow) * 264 + scol) = g1;
        }
        __syncthreads();
    }
}

// ---------------------------------------------------------------------------
// fp32 attention, Q projected per RQ-chunk (r10-verified; LDS <= 44160)
// ---------------------------------------------------------------------------
template <int LQ, int LK, int RQ>
__device__ void attn_body(int bx, const float* __restrict__ Xq,
                          const float* __restrict__ Xkv,
                          const float* __restrict__ Wi, const float* __restrict__ Bi,
                          float* __restrict__ O, float* __restrict__ sm)
{
    const int b   = bx >> 3;
    const int h   = bx & 7;
    const int tid = threadIdx.x;

    float* KsP = sm;                    // [LK][33]
    float* VsP = KsP + LK * 33;         // [LK][33]
    float* QsP = VsP + LK * 33;         // [RQ][33]
    float* SP  = QsP + RQ * 33;         // [RQ][LK+1]

    const float* xq  = Xq  + (size_t)b * LQ * DIM;
    const float* xkv = Xkv + (size_t)b * LK * DIM;

    {   // K/V projection
        const int col   = tid & 63;
        const int which = col >> 5;
        const int d     = col & 31;
        const int row   = DIM + which * DIM + h * HD + d;
        const float4* wr = (const float4*)(Wi + (size_t)row * DIM);
        const float bias = Bi[row];
        constexpr int TT = LK / 4;
        float acc[TT];
#pragma unroll
        for (int i = 0; i < TT; ++i) acc[i] = 0.f;
        const int t0 = tid >> 6;
        for (int k4 = 0; k4 < DIM / 4; ++k4) {
            const float4 w = wr[k4];
#pragma unroll
            for (int i = 0; i < TT; ++i) {
                const int t = t0 + 4 * i;
                const float4 aa = ((const float4*)(xkv + (size_t)t * DIM))[k4];
                acc[i] += dot4(aa, w);
            }
        }
#pragma unroll
        for (int i = 0; i < TT; ++i) {
            const int t = t0 + 4 * i;
            if (which == 0) KsP[t * 33 + d] = acc[i] + bias;
            else            VsP[t * 33 + d] = acc[i] + bias;
        }
    }
    __syncthreads();

    for (int q0 = 0; q0 < LQ; q0 += RQ) {
        {   // Q projection for this chunk
            const int d  = tid & 31;
            const int rg = tid >> 5;                // 0..7
            const int row = h * HD + d;
            const float4* wr = (const float4*)(Wi + (size_t)row * DIM);
            const float bias = Bi[row];
#pragma unroll
            for (int i = 0; i < RQ / 8; ++i) {
                const int rloc = rg + 8 * i;
                float acc = 0.f;
                const float4* xr = (const float4*)(xq + (size_t)(q0 + rloc) * DIM);
                for (int k4 = 0; k4 < DIM / 4; ++k4) acc += dot4(xr[k4], wr[k4]);
                QsP[rloc * 33 + d] = (acc + bias) * SCALE;
            }
        }
        __syncthreads();
        for (int idx = tid; idx < RQ * LK; idx += 256) {
            const int r = idx / LK;
            const int j = idx - r * LK;
            float acc = 0.f;
#pragma unroll
            for (int d = 0; d < HD; ++d)
                acc += QsP[r * 33 + d] * KsP[j * 33 + d];
            SP[r * (LK + 1) + j] = acc;
        }
        __syncthreads();
        if (tid < RQ * 8) {
            const int r   = tid >> 3;
            const int sub = tid & 7;
            float m = -1e30f;
            for (int j = sub; j < LK; j += 8) m = fmaxf(m, SP[r * (LK + 1) + j]);
#pragma unroll
            for (int off = 4; off; off >>= 1) m = fmaxf(m, __shfl_xor(m, off, 8));
            float sum = 0.f;
            for (int j = sub; j < LK; j += 8) {
                const float p = __expf(SP[r * (LK + 1) + j] - m);
                SP[r * (LK + 1) + j] = p;
                sum += p;
            }
#pragma unroll
            for (int off = 4; off; off >>= 1) sum += __shfl_xor(sum, off, 8);
            const float inv = 1.0f / sum;
            for (int j = sub; j < LK; j += 8) SP[r * (LK + 1) + j] *= inv;
        }
        __syncthreads();
        for (int idx = tid; idx < RQ * HD; idx += 256) {
            const int r = idx >> 5;
            const int d = idx & 31;
            float acc = 0.f;
            for (int j = 0; j < LK; ++j)
                acc += SP[r * (LK + 1) + j] * VsP[j * 33 + d];
            O[((size_t)(b * LQ + q0 + r)) * DIM + h * HD + d] = acc;
        }
        __syncthreads();
    }
}

// ---------------------------------------------------------------------------
// fused_main (52224 B dyn LDS -> 3 blocks/CU)
// ---------------------------------------------------------------------------
__global__ __launch_bounds__(256, 3) void fused_main(
    const float* __restrict__ leaf, const float* __restrict__ inner,
    const float* __restrict__ root,
    const float* __restrict__ w_in, const float* __restrict__ b_in,
    const float* __restrict__ b_out,
    const __bf16* __restrict__ W1b, const __bf16* __restrict__ W4kvb,
    const __bf16* __restrict__ Wv0b, const __bf16* __restrict__ Wo0b,
    __bf16* __restrict__ O1, float* __restrict__ Oc, float* __restrict__ tP,
    float* __restrict__ Op, float* __restrict__ Osf,
    float* __restrict__ Ors, float* __restrict__ Orc)
{
    extern __shared__ __align__(16) char smem[];
    const int bid = blockIdx.x;
    const size_t WI = 768 * 256, BI = 768;
    if (bid < 128)
        attn_body<128, 128, 16>(bid, inner, inner, w_in + 3 * WI, b_in + 3 * BI,
                                Osf, (float*)smem);
    else if (bid < 256)
        attn_body<128, 16, 32>(bid - 128, inner, root, w_in + 2 * WI, b_in + 2 * BI,
                               Op, (float*)smem);
    else if (bid < 384)
        attn_body<16, 128, 16>(bid - 256, root, inner, w_in + 5 * WI, b_in + 5 * BI,
                               Orc, (float*)smem);
    else if (bid < 512)
        attn_body<16, 16, 16>(bid - 384, root, root, w_in + 5 * WI, b_in + 5 * BI,
                              Ors, (float*)smem);
    else if (bid < 544)
        leafp_mfma_body(bid - 512, inner, Wv0b, Wo0b, b_in, b_out, tP, smem);
    else
        mega2_body(bid - 544, leaf, inner, W1b, b_in + 1 * BI, W4kvb,
                   w_in + 4 * WI, b_in + 4 * BI, O1, Oc, smem);
}

// ---------------------------------------------------------------------------
// combleaf body (r17 verbatim) + combines, merged into one epilogue launch.
// ---------------------------------------------------------------------------
__device__ void combleaf_body(int bid, const __bf16* __restrict__ O1,
    const __bf16* __restrict__ Wo1, const float* __restrict__ Bo1,
    const float* __restrict__ tP, const float* __restrict__ wleaf,
    float* __restrict__ out, char* __restrict__ smem)
{
    __bf16* Ws = (__bf16*)smem;             // [256][264]
    const int tid  = threadIdx.x;
    const int wid  = tid >> 6;              // 0..7 (wave = one leaf tile)
    const int lane = tid & 63;
    const int lr   = lane & 15;
    const int lk   = (lane >> 4) * 8;
    const int prow = (lane >> 4) * 4;

    bf16x8 a[4][8];
#pragma unroll
    for (int tg = 0; tg < 4; ++tg) {
        const __bf16* ar = O1 + ((size_t)bid * 512 + wid * 64 + tg * 16 + lr) * DIM + lk;
#pragma unroll
        for (int k = 0; k < 8; ++k) a[tg][k] = *(const bf16x8*)(ar + k * 32);
    }
    {
        const int row = tid >> 1, hf = tid & 1;
        const __bf16* p = Wo1 + (size_t)row * DIM + hf * 128;
        __bf16* dst = Ws + (size_t)row * 264 + hf * 128;
#pragma unroll
        for (int q = 0; q < 16; ++q)
            *(bf16x8*)(dst + q * 8) = *(const bf16x8*)(p + q * 8);
    }
    __syncthreads();

    const float e0 = __expf(wleaf[0]), e1 = __expf(wleaf[1]);
    const float wl0 = e0 / (e0 + e1), wl1 = e1 / (e0 + e1);
    const int   tile = bid * 8 + wid;
    const size_t rb  = (size_t)bid * 512 + wid * 64;

    for (int nt = 0; nt < 16; ++nt) {
        bf16x8 bw[8];
#pragma unroll
        for (int k = 0; k < 8; ++k)
            bw[k] = *(const bf16x8*)(Ws + (size_t)(nt * 16 + lr) * 264 + k * 32 + lk);
        f32x4 acc0 = {0.f,0.f,0.f,0.f}, acc1 = {0.f,0.f,0.f,0.f};
        f32x4 acc2 = {0.f,0.f,0.f,0.f}, acc3 = {0.f,0.f,0.f,0.f};
#pragma unroll
        for (int k = 0; k < 8; ++k) {
            acc0 = __builtin_amdgcn_mfma_f32_16x16x32_bf16(a[0][k], bw[k], acc0, 0, 0, 0);
            acc1 = __builtin_amdgcn_mfma_f32_16x16x32_bf16(a[1][k], bw[k], acc1, 0, 0, 0);
            acc2 = __builtin_amdgcn_mfma_f32_16x16x32_bf16(a[2][k], bw[k], acc2, 0, 0, 0);
            acc3 = __builtin_amdgcn_mfma_f32_16x16x32_bf16(a[3][k], bw[k], acc3, 0, 0, 0);
        }
        f32x4 accT[4] = { acc0, acc1, acc2, acc3 };
        const int   o  = nt * 16 + lr;
        const float bo = Bo1[o];
        const float tv = tP[(size_t)tile * DIM + o];
#pragma unroll
        for (int tg = 0; tg < 4; ++tg)
#pragma unroll
            for (int r = 0; r < 4; ++r)
                out[(rb + tg * 16 + prow + r) * DIM + o] =
                    wl0 * tv + wl1 * (accT[tg][r] + bo);
    }
}

__device__ void combine_inner_body(int vb, const float* __restrict__ Op,
    const float* __restrict__ Osf, const float* __restrict__ Oc,
    const float* __restrict__ W2, const float* __restrict__ B2,
    const float* __restrict__ W3, const float* __restrict__ B3,
    const float* __restrict__ W4, const float* __restrict__ B4,
    const float* __restrict__ winner, float* __restrict__ out, float* __restrict__ Ts)
{
    const int n0 = vb * 32;
    const int o  = threadIdx.x & 255;
    const float e0 = __expf(winner[0]), e1 = __expf(winner[1]), e2 = __expf(winner[2]);
    const float inv = 1.f / (e0 + e1 + e2);
    const float wt0 = e0 * inv, wt1 = e1 * inv, wt2 = e2 * inv;

    float acc[32];
#pragma unroll
    for (int r = 0; r < 32; ++r) acc[r] = 0.f;
    const float biasacc = wt0 * B2[o] + wt1 * B3[o] + wt2 * B4[o];

#pragma unroll
    for (int term = 0; term < 3; ++term) {
        const float* Ob = (term == 0) ? Op : (term == 1) ? Osf : Oc;
        const float* Wb = (term == 0) ? W2 : (term == 1) ? W3 : W4;
        const float wt  = (term == 0) ? wt0 : (term == 1) ? wt1 : wt2;
        __syncthreads();
        for (int idx = threadIdx.x; idx < 32 * DIM; idx += 256)
            Ts[idx] = Ob[(size_t)n0 * DIM + idx];
        __syncthreads();
        const float4* wr = (const float4*)(Wb + (size_t)o * DIM);
        for (int k4 = 0; k4 < DIM / 4; ++k4) {
            float4 w = wr[k4];
            w.x *= wt; w.y *= wt; w.z *= wt; w.w *= wt;
#pragma unroll
            for (int r = 0; r < 32; ++r) {
                const float4 aa = *(const float4*)&Ts[r * DIM + k4 * 4];
                acc[r] += dot4(aa, w);
            }
        }
    }
#pragma unroll
    for (int r = 0; r < 32; ++r)
        out[(size_t)(n0 + r) * DIM + o] = acc[r] + biasacc;
}

__device__ void combine_root_body(int vb, const float* __restrict__ Ors,
    const float* __restrict__ Orc, const float* __restrict__ W5,
    const float* __restrict__ B5, const float* __restrict__ wroot,
    float* __restrict__ out, float* __restrict__ Ts)
{
    const int n0 = vb * 32;
    const int o  = threadIdx.x & 255;
    const float e0 = __expf(wroot[0]), e1 = __expf(wroot[1]);
    const float w0 = e0 / (e0 + e1), w1 = e1 / (e0 + e1);
    for (int idx = threadIdx.x; idx < 32 * DIM; idx += 256)
        Ts[idx] = w0 * Ors[(size_t)n0 * DIM + idx] + w1 * Orc[(size_t)n0 * DIM + idx];
    __syncthreads();
    float acc[32];
#pragma unroll
    for (int r = 0; r < 32; ++r) acc[r] = 0.f;
    const float4* wr = (const float4*)(W5 + (size_t)o * DIM);
    for (int k4 = 0; k4 < DIM / 4; ++k4) {
        const float4 w = wr[k4];
#pragma unroll
        for (int r = 0; r < 32; ++r) {
            const float4 aa = *(const float4*)&Ts[r * DIM + k4 * 4];
            acc[r] += dot4(aa, w);
        }
    }
    const float bo = B5[o];
#pragma unroll
    for (int r = 0; r < 32; ++r)
        out[(size_t)(n0 + r) * DIM + o] = acc[r] + bo;
}

// epilogue: 256 combleaf blocks (512 thr each use all) + 72 combine blocks
// (only first 256 threads active in bodies' loops via tid&255 / strides).
__global__ __launch_bounds__(512) void epilogue_kernel(
    const __bf16* __restrict__ O1, const __bf16* __restrict__ Wo1b,
    const float* __restrict__ w_out, const float* __restrict__ b_out,
    const float* __restrict__ tP, const float* __restrict__ Op,
    const float* __restrict__ Osf, const float* __restrict__ Oc,
    const float* __restrict__ Ors, const float* __restrict__ Orc,
    const float* __restrict__ wleaf, const float* __restrict__ winner,
    const float* __restrict__ wroot, float* __restrict__ out)
{
    extern __shared__ __align__(16) char smem[];
    const int bid = blockIdx.x;
    const size_t WO = 256 * 256, BO = 256;
    if (bid < 256) {
        combleaf_body(bid, O1, Wo1b, b_out + BO, tP, wleaf, out, smem);
    } else if (bid < 320) {
        if (threadIdx.x < 256)
            combine_inner_body(bid - 256, Op, Osf, Oc,
                               w_out + 2 * WO, b_out + 2 * BO,
                               w_out + 3 * WO, b_out + 3 * BO,
                               w_out + 4 * WO, b_out + 4 * BO,
                               winner, out + 33554432, (float*)smem);
        else {
            // idle half-block must still hit the body's __syncthreads count:
            // combine_inner has 6 barriers (2 per term)
#pragma unroll
            for (int i = 0; i < 6; ++i) __syncthreads();
        }
    } else {
        if (threadIdx.x < 256)
            combine_root_body(bid - 320, Ors, Orc, w_out + 5 * WO, b_out + 5 * BO,
                              wroot, out + 33554432 + 524288, (float*)smem);
        else
            __syncthreads();                 // combine_root has 1 barrier
    }
}

// ---------------------------------------------------------------------------
extern "C" void kernel_launch(void* const* d_in, const int* in_sizes, int n_in,
                              void* d_out, int out_size, void* d_ws, size_t ws_size,
                              hipStream_t stream)
{
    const float* leaf   = (const float*)d_in[0];
    const float* inner  = (const float*)d_in[1];
    const float* root   = (const float*)d_in[2];
    const float* w_in   = (const float*)d_in[3];
    const float* b_in   = (const float*)d_in[4];
    const float* w_out  = (const float*)d_in[5];
    const float* b_out  = (const float*)d_in[6];
    const float* wleaf  = (const float*)d_in[7];
    const float* winner = (const float*)d_in[8];
    const float* wroot  = (const float*)d_in[9];
    float* out = (float*)d_out;

    // ws layout
    char* ws = (char*)d_ws;
    __bf16* W1b   = (__bf16*)(ws);                    // 393216 B
    __bf16* W4kvb = (__bf16*)(ws + 393216);           // 262144 B
    __bf16* Wo1b  = (__bf16*)(ws + 655360);           // 131072 B
    __bf16* Wv0b  = (__bf16*)(ws + 786432);           // 131072 B
    __bf16* Wo0b  = (__bf16*)(ws + 917504);           // 131072 B
    __bf16* O1b   = (__bf16*)(ws + 1048576);          // 67108864 B
    float*  tP    = (float*)(ws + 68157440);          // 2097152 B
    float*  Oc    = (float*)(ws + 70254592);
    float*  Op    = (float*)(ws + 72351744);
    float*  Osf   = (float*)(ws + 74448896);
    float*  Ors   = (float*)(ws + 76546048);
    float*  Orc   = (float*)(ws + 76808192);

    // merged weight conversion (1 launch)
    cvt_all<<<512, 256, 0, stream>>>(w_in, w_out, W1b, W4kvb, Wo1b, Wv0b, Wo0b);

    // fused main: aux (4 attn + leafp) + mega2 (overlaid LDS, 3 blocks/CU)
    fused_main<<<8736, 256, 52224, stream>>>(
        leaf, inner, root, w_in, b_in, b_out, W1b, W4kvb, Wv0b, Wo0b,
        O1b, Oc, tP, Op, Osf, Ors, Orc);

    // merged epilogue: combleaf + combine_inner + combine_root
    epilogue_kernel<<<328, 512, 135168, stream>>>(O1b, Wo1b, w_out, b_out, tP,
                                                  Op, Osf, Oc, Ors, Orc,
                                                  wleaf, winner, wroot, out);
}

// Round 19
// 768.671 us; speedup vs baseline: 1.2012x; 1.2012x over previous
//
#include <hip/hip_runtime.h>
#include <hip/hip_bf16.h>
#include <cstdint>

// AttnLayerBU round 19: r18 with the register-allocation fix — fused_main
// uses __launch_bounds__(256) (no min-waves hint). r18's (256,3) capped
// VGPR at 84 and spilled the A-fragment working set to scratch (+195MB
// writes). 3 blocks/CU still achieved via the 52224 B LDS footprint.

#define DIM 256
#define NH 8
#define HD 32

static constexpr float SCALE = 0.17677669529663687f; // 32^-0.5

typedef __bf16 bf16x8 __attribute__((ext_vector_type(8)));
typedef __bf16 bf16x4 __attribute__((ext_vector_type(4)));
typedef float  f32x4  __attribute__((ext_vector_type(4)));

__device__ __forceinline__ float dot4(const float4 a, const float4 b) {
    return a.x * b.x + a.y * b.y + a.z * b.z + a.w * b.w;
}

// ---------------------------------------------------------------------------
// merged weight converter: 5 ranges in one launch
// ---------------------------------------------------------------------------
__device__ __forceinline__ void cvt_range(const float* __restrict__ s,
                                          __bf16* __restrict__ d, int lb, int n) {
    int i = (lb * 256 + (int)threadIdx.x) * 4;
    if (i < n) {
        float4 v = *(const float4*)(s + i);
        d[i + 0] = (__bf16)v.x; d[i + 1] = (__bf16)v.y;
        d[i + 2] = (__bf16)v.z; d[i + 3] = (__bf16)v.w;
    }
}

__global__ __launch_bounds__(256) void cvt_all(
    const float* __restrict__ w_in, const float* __restrict__ w_out,
    __bf16* __restrict__ W1b, __bf16* __restrict__ W4kvb,
    __bf16* __restrict__ Wo1b, __bf16* __restrict__ Wv0b,
    __bf16* __restrict__ Wo0b)
{
    const size_t WI = 768 * 256, WO = 256 * 256;
    const int bid = blockIdx.x;
    if (bid < 192)       cvt_range(w_in + 1 * WI, W1b, bid, 768 * 256);
    else if (bid < 320)  cvt_range(w_in + 4 * WI + 256 * 256, W4kvb, bid - 192, 512 * 256);
    else if (bid < 384)  cvt_range(w_out + 1 * WO, Wo1b, bid - 320, 256 * 256);
    else if (bid < 448)  cvt_range(w_in + 512 * 256, Wv0b, bid - 384, 256 * 256);
    else                 cvt_range(w_out, Wo0b, bid - 448, 256 * 256);
}

// ---------------------------------------------------------------------------
// mega2 body. LDS (52224 B):
//   region A [0,33792): Xs[64][264] during staging; after af-load barrier:
//     Qs[64][72]@0 (Pw 4x[16][72] overlays Qs after pre-PV barrier),
//     Ks[64][72]@9216, K4t[64][72]@18432, scratch f32 @27648 (2304)
//   Vt[64][72]@33792   V4t[64][72]@43008
// ---------------------------------------------------------------------------
__device__ void mega2_body(int g,
    const float* __restrict__ X, const float* __restrict__ inner,
    const __bf16* __restrict__ W1b, const float* __restrict__ Bi1,
    const __bf16* __restrict__ W4kvb, const float* __restrict__ W4q,
    const float* __restrict__ Bi4, __bf16* __restrict__ O1,
    float* __restrict__ Oc, char* __restrict__ smem)
{
    const int xcd  = g & 7;
    const int idx  = g >> 3;               // 0..1023
    const int b    = xcd * 256 + (idx >> 2);
    const int hg   = idx & 3;              // head-pair: heads 2hg, 2hg+1
    const int tid  = threadIdx.x;
    const int wid  = tid >> 6;             // 0..3
    const int lane = tid & 63;
    const int lr   = lane & 15;
    const int lk   = (lane >> 4) * 8;
    const int prow = (lane >> 4) * 4;

    __bf16* Xs  = (__bf16*)smem;                    // [64][264] (staging)
    __bf16* Qs  = (__bf16*)smem;                    // [64][72] overlay
    __bf16* Pw  = (__bf16*)(smem + wid * 2304);     // overlay on Qs (post-PV-barrier)
    __bf16* Ks  = (__bf16*)(smem + 9216);           // [64][72]
    __bf16* K4t = (__bf16*)(smem + 18432);          // [64col][72]
    float* qpart = (float*)(smem + 27648);          // [4][64]
    float* qv    = qpart + 256;                     // [64]
    float* psm   = qv + 64;                         // [2][64]
    float* opart = psm + 128;                       // [2][64]
    __bf16* Vt  = (__bf16*)(smem + 33792);          // [64 d][72 tok]
    __bf16* V4t = (__bf16*)(smem + 43008);          // [64col][72]

    // ---- stage X tile (fp32 -> bf16) into Xs, coalesced ----
    {
        const float* xb = X + (size_t)b * 64 * DIM;
#pragma unroll
        for (int it = 0; it < 16; ++it) {
            const int e4 = it * 1024 + tid * 4;
            const f32x4 v = __builtin_nontemporal_load((const f32x4*)(xb + e4));
            bf16x4 t4;
            t4[0] = (__bf16)v[0]; t4[1] = (__bf16)v[1];
            t4[2] = (__bf16)v[2]; t4[3] = (__bf16)v[3];
            const int row = e4 >> 8, col = e4 & 255;
            *(bf16x4*)(Xs + row * 264 + col) = t4;
        }
    }
    __syncthreads();                                 // b1: Xs ready

    // ---- load ALL A-fragments into registers: 4 row-groups x 8 k ----
    bf16x8 af[4][8];
#pragma unroll
    for (int tg = 0; tg < 4; ++tg)
#pragma unroll
        for (int kk = 0; kk < 8; ++kk)
            af[tg][kk] = *(const bf16x8*)(Xs + (size_t)(tg * 16 + lr) * 264 + kk * 32 + lk);
    __syncthreads();                                 // b2: Xs dead (overlay OK)

    // ---- projection: wave owns n-tiles wid*5..+4, A & B in regs, no barriers
    {
        auto wsrc = [&](int t) -> const __bf16* {
            if (t < 12) {
                const int sec = t >> 2, sub = t & 3;
                return W1b + (size_t)(sec * 256 + hg * 64 + sub * 16) * DIM;
            }
            const int u = t - 12, sec = u >> 2, sub = u & 3;
            return W4kvb + (size_t)(sec * 256 + hg * 64 + sub * 16) * DIM;
        };
        const size_t boff = (size_t)lr * DIM + lk;
        const int t0w = wid * 5;
        bf16x8 bw[8], bn[8];
        {
            const __bf16* p = wsrc(t0w) + boff;
#pragma unroll
            for (int kk = 0; kk < 8; ++kk) bw[kk] = *(const bf16x8*)(p + kk * 32);
        }
        for (int i = 0; i < 5; ++i) {
            const int t = t0w + i;
            if (i + 1 < 5) {
                const __bf16* p = wsrc(t + 1) + boff;
#pragma unroll
                for (int kk = 0; kk < 8; ++kk) bn[kk] = *(const bf16x8*)(p + kk * 32);
            }
            f32x4 acc0 = {0.f,0.f,0.f,0.f}, acc1 = {0.f,0.f,0.f,0.f};
            f32x4 acc2 = {0.f,0.f,0.f,0.f}, acc3 = {0.f,0.f,0.f,0.f};
#pragma unroll
            for (int kk = 0; kk < 8; ++kk) {
                acc0 = __builtin_amdgcn_mfma_f32_16x16x32_bf16(af[0][kk], bw[kk], acc0, 0, 0, 0);
                acc1 = __builtin_amdgcn_mfma_f32_16x16x32_bf16(af[1][kk], bw[kk], acc1, 0, 0, 0);
                acc2 = __builtin_amdgcn_mfma_f32_16x16x32_bf16(af[2][kk], bw[kk], acc2, 0, 0, 0);
                acc3 = __builtin_amdgcn_mfma_f32_16x16x32_bf16(af[3][kk], bw[kk], acc3, 0, 0, 0);
            }
            f32x4 accT[4] = { acc0, acc1, acc2, acc3 };
            const int sub = t & 3;
            const int col = sub * 16 + lr;
            if (t < 4) {                            // Q (scaled)
                const float bias = Bi1[hg * 64 + sub * 16 + lr];
#pragma unroll
                for (int tg = 0; tg < 4; ++tg)
#pragma unroll
                    for (int r = 0; r < 4; ++r)
                        Qs[(size_t)(tg * 16 + prow + r) * 72 + col] =
                            (__bf16)((accT[tg][r] + bias) * SCALE);
            } else if (t < 8) {                     // K
                const float bias = Bi1[256 + hg * 64 + sub * 16 + lr];
#pragma unroll
                for (int tg = 0; tg < 4; ++tg)
#pragma unroll
                    for (int r = 0; r < 4; ++r)
                        Ks[(size_t)(tg * 16 + prow + r) * 72 + col] =
                            (__bf16)(accT[tg][r] + bias);
            } else if (t < 12) {                    // V -> [d][tok]
                const float bias = Bi1[512 + hg * 64 + sub * 16 + lr];
#pragma unroll
                for (int tg = 0; tg < 4; ++tg) {
                    bf16x4 pv;
#pragma unroll
                    for (int r = 0; r < 4; ++r) pv[r] = (__bf16)(accT[tg][r] + bias);
                    *(bf16x4*)(Vt + (size_t)col * 72 + tg * 16 + prow) = pv;
                }
            } else if (t < 16) {                    // K4 -> [d][tok]
                const float bias = Bi4[256 + hg * 64 + sub * 16 + lr];
#pragma unroll
                for (int tg = 0; tg < 4; ++tg) {
                    bf16x4 pv;
#pragma unroll
                    for (int r = 0; r < 4; ++r) pv[r] = (__bf16)(accT[tg][r] + bias);
                    *(bf16x4*)(K4t + (size_t)col * 72 + tg * 16 + prow) = pv;
                }
            } else {                                // V4 -> [d][tok]
                const float bias = Bi4[512 + hg * 64 + sub * 16 + lr];
#pragma unroll
                for (int tg = 0; tg < 4; ++tg) {
                    bf16x4 pv;
#pragma unroll
                    for (int r = 0; r < 4; ++r) pv[r] = (__bf16)(accT[tg][r] + bias);
                    *(bf16x4*)(V4t + (size_t)col * 72 + tg * 16 + prow) = pv;
                }
            }
#pragma unroll
            for (int kk = 0; kk < 8; ++kk) bw[kk] = bn[kk];
        }
    }
    __syncthreads();                                 // b3: proj done

    // ---- inner_c q-projection partials ----
    {
        const int o = tid & 63, part = tid >> 6;
        const float4* wr = (const float4*)(W4q + (size_t)(hg * 64 + o) * DIM + part * 64);
        const float4* xr = (const float4*)(inner + (size_t)b * DIM + part * 64);
        float accq = 0.f;
#pragma unroll
        for (int k = 0; k < 16; ++k) accq += dot4(xr[k], wr[k]);
        qpart[part * 64 + o] = accq;
    }
    __syncthreads();                                 // b4

    if (tid < 64)
        qv[tid] = (qpart[tid] + qpart[64 + tid] + qpart[128 + tid] + qpart[192 + tid]
                   + Bi4[hg * 64 + tid]) * SCALE;

    // ---- leaf_s attention: wave = (head hh, q-half qh) ----
    const int hh = wid >> 1;
    const int qh = wid & 1;
    f32x4 s[2][4];
    {
        bf16x8 kb[4];
#pragma unroll
        for (int kt = 0; kt < 4; ++kt)
            kb[kt] = *(const bf16x8*)(Ks + (size_t)(kt * 16 + lr) * 72 + hh * 32 + lk);
#pragma unroll
        for (int q2 = 0; q2 < 2; ++q2) {
            const int qt = qh * 2 + q2;
            const bf16x8 qa = *(const bf16x8*)(Qs + (size_t)(qt * 16 + lr) * 72 + hh * 32 + lk);
#pragma unroll
            for (int kt = 0; kt < 4; ++kt) {
                f32x4 z = {0.f, 0.f, 0.f, 0.f};
                s[q2][kt] = __builtin_amdgcn_mfma_f32_16x16x32_bf16(qa, kb[kt], z, 0, 0, 0);
            }
        }
    }
#pragma unroll
    for (int q2 = 0; q2 < 2; ++q2) {
#pragma unroll
        for (int r = 0; r < 4; ++r) {
            float m = fmaxf(fmaxf(s[q2][0][r], s[q2][1][r]), fmaxf(s[q2][2][r], s[q2][3][r]));
#pragma unroll
            for (int off = 1; off < 16; off <<= 1) m = fmaxf(m, __shfl_xor(m, off));
            const float p0 = __expf(s[q2][0][r] - m), p1 = __expf(s[q2][1][r] - m);
            const float p2 = __expf(s[q2][2][r] - m), p3 = __expf(s[q2][3][r] - m);
            float t = p0 + p1 + p2 + p3;
#pragma unroll
            for (int off = 1; off < 16; off <<= 1) t += __shfl_xor(t, off);
            const float inv = 1.0f / t;
            s[q2][0][r] = p0 * inv; s[q2][1][r] = p1 * inv;
            s[q2][2][r] = p2 * inv; s[q2][3][r] = p3 * inv;
        }
    }
    bf16x8 vb[2][2];
#pragma unroll
    for (int dt = 0; dt < 2; ++dt)
#pragma unroll
        for (int ks = 0; ks < 2; ++ks)
            vb[dt][ks] = *(const bf16x8*)(Vt + (size_t)(hh * 32 + dt * 16 + lr) * 72 + ks * 32 + lk);
    __syncthreads();                                 // b5: Qs reads done (Pw overlay safe)

    {
#pragma unroll
        for (int q2 = 0; q2 < 2; ++q2) {
            const int qt = qh * 2 + q2;
#pragma unroll
            for (int kt = 0; kt < 4; ++kt)
#pragma unroll
                for (int r = 0; r < 4; ++r)
                    Pw[(size_t)(prow + r) * 72 + kt * 16 + lr] = (__bf16)s[q2][kt][r];
            bf16x8 pa[2];
#pragma unroll
            for (int ks = 0; ks < 2; ++ks)
                pa[ks] = *(const bf16x8*)(Pw + (size_t)lr * 72 + ks * 32 + lk);
#pragma unroll
            for (int dt = 0; dt < 2; ++dt) {
                f32x4 o = {0.f, 0.f, 0.f, 0.f};
#pragma unroll
                for (int ks = 0; ks < 2; ++ks)
                    o = __builtin_amdgcn_mfma_f32_16x16x32_bf16(pa[ks], vb[dt][ks], o, 0, 0, 0);
                const int colO = (hg * 2 + hh) * 32 + dt * 16 + lr;
#pragma unroll
                for (int r = 0; r < 4; ++r)
                    __builtin_nontemporal_store((__bf16)o[r],
                        &O1[((size_t)b * 64 + qt * 16 + prow + r) * DIM + colO]);
            }
        }
    }
    __syncthreads();                                 // b6: PV done, qv ready

    if (wid < 2) {
        const int j = lane;
        float sv = 0.f;
#pragma unroll
        for (int d = 0; d < 32; ++d)
            sv += qv[wid * 32 + d] * (float)K4t[(size_t)(wid * 32 + d) * 72 + j];
        float m = sv;
#pragma unroll
        for (int off = 1; off < 64; off <<= 1) m = fmaxf(m, __shfl_xor(m, off));
        const float p = __expf(sv - m);
        float t = p;
#pragma unroll
        for (int off = 1; off < 64; off <<= 1) t += __shfl_xor(t, off);
        psm[wid * 64 + j] = p / t;
    }
    __syncthreads();

    if (tid < 128) {
        const int o = tid & 63, hf = tid >> 6;
        const int ho = o >> 5;
        float acc2 = 0.f;
#pragma unroll
        for (int j = 0; j < 32; ++j)
            acc2 += psm[ho * 64 + hf * 32 + j] * (float)V4t[(size_t)o * 72 + hf * 32 + j];
        opart[hf * 64 + o] = acc2;
    }
    __syncthreads();
    if (tid < 64)
        Oc[(size_t)b * DIM + hg * 64 + tid] = opart[tid] + opart[64 + tid];
}

// ---------------------------------------------------------------------------
// leafp MFMA 2-stage (r12 verbatim; LDS 50688 <= 52224)
// ---------------------------------------------------------------------------
__device__ void leafp_mfma_body(int bid, const float* __restrict__ inner,
    const __bf16* __restrict__ Wv0b, const __bf16* __restrict__ Wo0b,
    const float* __restrict__ b_in0, const float* __restrict__ b_out0,
    float* __restrict__ tP, char* __restrict__ smem)
{
    __bf16* tV = (__bf16*)smem;             // [64][264]
    __bf16* Bs = (__bf16*)(smem + 33792);   // [2][16][264]
    const int tid  = threadIdx.x;
    const int wid  = tid >> 6;
    const int lane = tid & 63;
    const int lr   = lane & 15;
    const int lk   = (lane >> 4) * 8;
    const int prow = (lane >> 4) * 4;
    const int tok0 = wid * 16 + prow;
    const int srow = tid >> 5;
    const int scol = (tid & 31) * 8;

    bf16x8 a[8];
    {
        const float* xrow = inner + ((size_t)bid * 64 + wid * 16 + lr) * DIM + lk;
#pragma unroll
        for (int k = 0; k < 8; ++k) {
            float4 v0 = *(const float4*)(xrow + k * 32);
            float4 v1 = *(const float4*)(xrow + k * 32 + 4);
            bf16x8 t;
            t[0] = (__bf16)v0.x; t[1] = (__bf16)v0.y; t[2] = (__bf16)v0.z; t[3] = (__bf16)v0.w;
            t[4] = (__bf16)v1.x; t[5] = (__bf16)v1.y; t[6] = (__bf16)v1.z; t[7] = (__bf16)v1.w;
            a[k] = t;
        }
    }

    {
        bf16x8 g0 = *(const bf16x8*)(Wv0b + (size_t)srow * DIM + scol);
        bf16x8 g1 = *(const bf16x8*)(Wv0b + (size_t)(8 + srow) * DIM + scol);
        *(bf16x8*)(Bs + srow * 264 + scol) = g0;
        *(bf16x8*)(Bs + (8 + srow) * 264 + scol) = g1;
    }
    __syncthreads();
    for (int t = 0; t < 16; ++t) {
        const int cur = t & 1;
        const __bf16* Bc = Bs + cur * 4224;
        bf16x8 g0, g1;
        if (t + 1 < 16) {
            const __bf16* p = Wv0b + (size_t)((t + 1) * 16) * DIM;
            g0 = *(const bf16x8*)(p + (size_t)srow * DIM + scol);
            g1 = *(const bf16x8*)(p + (size_t)(8 + srow) * DIM + scol);
        }
        f32x4 acc = {0.f, 0.f, 0.f, 0.f};
#pragma unroll
        for (int k = 0; k < 8; ++k)
            acc = __builtin_amdgcn_mfma_f32_16x16x32_bf16(
                a[k], *(const bf16x8*)(Bc + lr * 264 + k * 32 + lk), acc, 0, 0, 0);
        const float bias = b_in0[512 + t * 16 + lr];
#pragma unroll
        for (int r = 0; r < 4; ++r)
            tV[(size_t)(tok0 + r) * 264 + t * 16 + lr] = (__bf16)(acc[r] + bias);
        if (t + 1 < 16) {
            __bf16* Bn = Bs + (cur ^ 1) * 4224;
            *(bf16x8*)(Bn + srow * 264 + scol) = g0;
            *(bf16x8*)(Bn + (8 + srow) * 264 + scol) = g1;
        }
        __syncthreads();
    }

    bf16x8 a2[8];
#pragma unroll
    for (int k = 0; k < 8; ++k)
        a2[k] = *(const bf16x8*)(tV + (size_t)(wid * 16 + lr) * 264 + k * 32 + lk);
    {
        bf16x8 g0 = *(const bf16x8*)(Wo0b + (size_t)srow * DIM + scol);
        bf16x8 g1 = *(const bf16x8*)(Wo0b + (size_t)(8 + srow) * DIM + scol);
        *(bf16x8*)(Bs + srow * 264 + scol) = g0;
        *(bf16x8*)(Bs + (8 + srow) * 264 + scol) = g1;
    }
    __syncthreads();
    for (int t = 0; t < 16; ++t) {
        const int cur = t & 1;
        const __bf16* Bc = Bs + cur * 4224;
        bf16x8 g0, g1;
        if (t + 1 < 16) {
            const __bf16* p = Wo0b + (size_t)((t + 1) * 16) * DIM;
            g0 = *(const bf16x8*)(p + (size_t)srow * DIM + scol);
            g1 = *(const bf16x8*)(p + (size_t)(8 + srow) * DIM + scol);
        }
        f32x4 acc = {0.f, 0.f, 0.f, 0.f};
#pragma unroll
        for (int k = 0; k < 8; ++k)
            acc = __builtin_amdgcn_mfma_f32_16x16x32_bf16(
                a2[k], *(const bf16x8*)(Bc + lr * 264 + k * 32 + lk), acc, 0, 0, 0);
        const float bo = b_out0[t * 16 + lr];
#pragma unroll
        for (int r = 0; r < 4; ++r)
            tP[((size_t)bid * 64 + wid * 16 + prow + r) * DIM + t * 16 + lr] = acc[r] + bo;
        if (t + 1 < 16) {
            __bf16* Bn = Bs + (cur ^ 1) * 4224;
            *(bf16x8*)(Bn + srow * 264 + scol) = g0;
            *(bf16x8*)(Bn + (8 + srow) * 264 + scol) = g1;
        }
        __syncthreads();
    }
}

// ---------------------------------------------------------------------------
// fp32 attention, Q projected per RQ-chunk (r10-verified; LDS <= 44160)
// ---------------------------------------------------------------------------
template <int LQ, int LK, int RQ>
__device__ void attn_body(int bx, const float* __restrict__ Xq,
                          const float* __restrict__ Xkv,
                          const float* __restrict__ Wi, const float* __restrict__ Bi,
                          float* __restrict__ O, float* __restrict__ sm)
{
    const int b   = bx >> 3;
    const int h   = bx & 7;
    const int tid = threadIdx.x;

    float* KsP = sm;                    // [LK][33]
    float* VsP = KsP + LK * 33;         // [LK][33]
    float* QsP = VsP + LK * 33;         // [RQ][33]
    float* SP  = QsP + RQ * 33;         // [RQ][LK+1]

    const float* xq  = Xq  + (size_t)b * LQ * DIM;
    const float* xkv = Xkv + (size_t)b * LK * DIM;

    {   // K/V projection
        const int col   = tid & 63;
        const int which = col >> 5;
        const int d     = col & 31;
        const int row   = DIM + which * DIM + h * HD + d;
        const float4* wr = (const float4*)(Wi + (size_t)row * DIM);
        const float bias = Bi[row];
        constexpr int TT = LK / 4;
        float acc[TT];
#pragma unroll
        for (int i = 0; i < TT; ++i) acc[i] = 0.f;
        const int t0 = tid >> 6;
        for (int k4 = 0; k4 < DIM / 4; ++k4) {
            const float4 w = wr[k4];
#pragma unroll
            for (int i = 0; i < TT; ++i) {
                const int t = t0 + 4 * i;
                const float4 aa = ((const float4*)(xkv + (size_t)t * DIM))[k4];
                acc[i] += dot4(aa, w);
            }
        }
#pragma unroll
        for (int i = 0; i < TT; ++i) {
            const int t = t0 + 4 * i;
            if (which == 0) KsP[t * 33 + d] = acc[i] + bias;
            else            VsP[t * 33 + d] = acc[i] + bias;
        }
    }
    __syncthreads();

    for (int q0 = 0; q0 < LQ; q0 += RQ) {
        {   // Q projection for this chunk
            const int d  = tid & 31;
            const int rg = tid >> 5;                // 0..7
            const int row = h * HD + d;
            const float4* wr = (const float4*)(Wi + (size_t)row * DIM);
            const float bias = Bi[row];
#pragma unroll
            for (int i = 0; i < RQ / 8; ++i) {
                const int rloc = rg + 8 * i;
                float acc = 0.f;
                const float4* xr = (const float4*)(xq + (size_t)(q0 + rloc) * DIM);
                for (int k4 = 0; k4 < DIM / 4; ++k4) acc += dot4(xr[k4], wr[k4]);
                QsP[rloc * 33 + d] = (acc + bias) * SCALE;
            }
        }
        __syncthreads();
        for (int idx = tid; idx < RQ * LK; idx += 256) {
            const int r = idx / LK;
            const int j = idx - r * LK;
            float acc = 0.f;
#pragma unroll
            for (int d = 0; d < HD; ++d)
                acc += QsP[r * 33 + d] * KsP[j * 33 + d];
            SP[r * (LK + 1) + j] = acc;
        }
        __syncthreads();
        if (tid < RQ * 8) {
            const int r   = tid >> 3;
            const int sub = tid & 7;
            float m = -1e30f;
            for (int j = sub; j < LK; j += 8) m = fmaxf(m, SP[r * (LK + 1) + j]);
#pragma unroll
            for (int off = 4; off; off >>= 1) m = fmaxf(m, __shfl_xor(m, off, 8));
            float sum = 0.f;
            for (int j = sub; j < LK; j += 8) {
                const float p = __expf(SP[r * (LK + 1) + j] - m);
                SP[r * (LK + 1) + j] = p;
                sum += p;
            }
#pragma unroll
            for (int off = 4; off; off >>= 1) sum += __shfl_xor(sum, off, 8);
            const float inv = 1.0f / sum;
            for (int j = sub; j < LK; j += 8) SP[r * (LK + 1) + j] *= inv;
        }
        __syncthreads();
        for (int idx = tid; idx < RQ * HD; idx += 256) {
            const int r = idx >> 5;
            const int d = idx & 31;
            float acc = 0.f;
            for (int j = 0; j < LK; ++j)
                acc += SP[r * (LK + 1) + j] * VsP[j * 33 + d];
            O[((size_t)(b * LQ + q0 + r)) * DIM + h * HD + d] = acc;
        }
        __syncthreads();
    }
}

// ---------------------------------------------------------------------------
// fused_main (52224 B dyn LDS -> 3 blocks/CU; NO min-waves hint)
// ---------------------------------------------------------------------------
__global__ __launch_bounds__(256) void fused_main(
    const float* __restrict__ leaf, const float* __restrict__ inner,
    const float* __restrict__ root,
    const float* __restrict__ w_in, const float* __restrict__ b_in,
    const float* __restrict__ b_out,
    const __bf16* __restrict__ W1b, const __bf16* __restrict__ W4kvb,
    const __bf16* __restrict__ Wv0b, const __bf16* __restrict__ Wo0b,
    __bf16* __restrict__ O1, float* __restrict__ Oc, float* __restrict__ tP,
    float* __restrict__ Op, float* __restrict__ Osf,
    float* __restrict__ Ors, float* __restrict__ Orc)
{
    extern __shared__ __align__(16) char smem[];
    const int bid = blockIdx.x;
    const size_t WI = 768 * 256, BI = 768;
    if (bid < 128)
        attn_body<128, 128, 16>(bid, inner, inner, w_in + 3 * WI, b_in + 3 * BI,
                                Osf, (float*)smem);
    else if (bid < 256)
        attn_body<128, 16, 32>(bid - 128, inner, root, w_in + 2 * WI, b_in + 2 * BI,
                               Op, (float*)smem);
    else if (bid < 384)
        attn_body<16, 128, 16>(bid - 256, root, inner, w_in + 5 * WI, b_in + 5 * BI,
                               Orc, (float*)smem);
    else if (bid < 512)
        attn_body<16, 16, 16>(bid - 384, root, root, w_in + 5 * WI, b_in + 5 * BI,
                              Ors, (float*)smem);
    else if (bid < 544)
        leafp_mfma_body(bid - 512, inner, Wv0b, Wo0b, b_in, b_out, tP, smem);
    else
        mega2_body(bid - 544, leaf, inner, W1b, b_in + 1 * BI, W4kvb,
                   w_in + 4 * WI, b_in + 4 * BI, O1, Oc, smem);
}

// ---------------------------------------------------------------------------
// combleaf body (r17 verbatim) + combines, merged into one epilogue launch.
// ---------------------------------------------------------------------------
__device__ void combleaf_body(int bid, const __bf16* __restrict__ O1,
    const __bf16* __restrict__ Wo1, const float* __restrict__ Bo1,
    const float* __restrict__ tP, const float* __restrict__ wleaf,
    float* __restrict__ out, char* __restrict__ smem)
{
    __bf16* Ws = (__bf16*)smem;             // [256][264]
    const int tid  = threadIdx.x;
    const int wid  = tid >> 6;              // 0..7 (wave = one leaf tile)
    const int lane = tid & 63;
    const int lr   = lane & 15;
    const int lk   = (lane >> 4) * 8;
    const int prow = (lane >> 4) * 4;

    bf16x8 a[4][8];
#pragma unroll
    for (int tg = 0; tg < 4; ++tg) {
        const __bf16* ar = O1 + ((size_t)bid * 512 + wid * 64 + tg * 16 + lr) * DIM + lk;
#pragma unroll
        for (int k = 0; k < 8; ++k) a[tg][k] = *(const bf16x8*)(ar + k * 32);
    }
    {
        const int row = tid >> 1, hf = tid & 1;
        const __bf16* p = Wo1 + (size_t)row * DIM + hf * 128;
        __bf16* dst = Ws + (size_t)row * 264 + hf * 128;
#pragma unroll
        for (int q = 0; q < 16; ++q)
            *(bf16x8*)(dst + q * 8) = *(const bf16x8*)(p + q * 8);
    }
    __syncthreads();

    const float e0 = __expf(wleaf[0]), e1 = __expf(wleaf[1]);
    const float wl0 = e0 / (e0 + e1), wl1 = e1 / (e0 + e1);
    const int   tile = bid * 8 + wid;
    const size_t rb  = (size_t)bid * 512 + wid * 64;

    for (int nt = 0; nt < 16; ++nt) {
        bf16x8 bw[8];
#pragma unroll
        for (int k = 0; k < 8; ++k)
            bw[k] = *(const bf16x8*)(Ws + (size_t)(nt * 16 + lr) * 264 + k * 32 + lk);
        f32x4 acc0 = {0.f,0.f,0.f,0.f}, acc1 = {0.f,0.f,0.f,0.f};
        f32x4 acc2 = {0.f,0.f,0.f,0.f}, acc3 = {0.f,0.f,0.f,0.f};
#pragma unroll
        for (int k = 0; k < 8; ++k) {
            acc0 = __builtin_amdgcn_mfma_f32_16x16x32_bf16(a[0][k], bw[k], acc0, 0, 0, 0);
            acc1 = __builtin_amdgcn_mfma_f32_16x16x32_bf16(a[1][k], bw[k], acc1, 0, 0, 0);
            acc2 = __builtin_amdgcn_mfma_f32_16x16x32_bf16(a[2][k], bw[k], acc2, 0, 0, 0);
            acc3 = __builtin_amdgcn_mfma_f32_16x16x32_bf16(a[3][k], bw[k], acc3, 0, 0, 0);
        }
        f32x4 accT[4] = { acc0, acc1, acc2, acc3 };
        const int   o  = nt * 16 + lr;
        const float bo = Bo1[o];
        const float tv = tP[(size_t)tile * DIM + o];
#pragma unroll
        for (int tg = 0; tg < 4; ++tg)
#pragma unroll
            for (int r = 0; r < 4; ++r)
                out[(rb + tg * 16 + prow + r) * DIM + o] =
                    wl0 * tv + wl1 * (accT[tg][r] + bo);
    }
}

__device__ void combine_inner_body(int vb, const float* __restrict__ Op,
    const float* __restrict__ Osf, const float* __restrict__ Oc,
    const float* __restrict__ W2, const float* __restrict__ B2,
    const float* __restrict__ W3, const float* __restrict__ B3,
    const float* __restrict__ W4, const float* __restrict__ B4,
    const float* __restrict__ winner, float* __restrict__ out, float* __restrict__ Ts)
{
    const int n0 = vb * 32;
    const int o  = threadIdx.x & 255;
    const float e0 = __expf(winner[0]), e1 = __expf(winner[1]), e2 = __expf(winner[2]);
    const float inv = 1.f / (e0 + e1 + e2);
    const float wt0 = e0 * inv, wt1 = e1 * inv, wt2 = e2 * inv;

    float acc[32];
#pragma unroll
    for (int r = 0; r < 32; ++r) acc[r] = 0.f;
    const float biasacc = wt0 * B2[o] + wt1 * B3[o] + wt2 * B4[o];

#pragma unroll
    for (int term = 0; term < 3; ++term) {
        const float* Ob = (term == 0) ? Op : (term == 1) ? Osf : Oc;
        const float* Wb = (term == 0) ? W2 : (term == 1) ? W3 : W4;
        const float wt  = (term == 0) ? wt0 : (term == 1) ? wt1 : wt2;
        __syncthreads();
        for (int idx = threadIdx.x; idx < 32 * DIM; idx += 256)
            Ts[idx] = Ob[(size_t)n0 * DIM + idx];
        __syncthreads();
        const float4* wr = (const float4*)(Wb + (size_t)o * DIM);
        for (int k4 = 0; k4 < DIM / 4; ++k4) {
            float4 w = wr[k4];
            w.x *= wt; w.y *= wt; w.z *= wt; w.w *= wt;
#pragma unroll
            for (int r = 0; r < 32; ++r) {
                const float4 aa = *(const float4*)&Ts[r * DIM + k4 * 4];
                acc[r] += dot4(aa, w);
            }
        }
    }
#pragma unroll
    for (int r = 0; r < 32; ++r)
        out[(size_t)(n0 + r) * DIM + o] = acc[r] + biasacc;
}

__device__ void combine_root_body(int vb, const float* __restrict__ Ors,
    const float* __restrict__ Orc, const float* __restrict__ W5,
    const float* __restrict__ B5, const float* __restrict__ wroot,
    float* __restrict__ out, float* __restrict__ Ts)
{
    const int n0 = vb * 32;
    const int o  = threadIdx.x & 255;
    const float e0 = __expf(wroot[0]), e1 = __expf(wroot[1]);
    const float w0 = e0 / (e0 + e1), w1 = e1 / (e0 + e1);
    for (int idx = threadIdx.x; idx < 32 * DIM; idx += 256)
        Ts[idx] = w0 * Ors[(size_t)n0 * DIM + idx] + w1 * Orc[(size_t)n0 * DIM + idx];
    __syncthreads();
    float acc[32];
#pragma unroll
    for (int r = 0; r < 32; ++r) acc[r] = 0.f;
    const float4* wr = (const float4*)(W5 + (size_t)o * DIM);
    for (int k4 = 0; k4 < DIM / 4; ++k4) {
        const float4 w = wr[k4];
#pragma unroll
        for (int r = 0; r < 32; ++r) {
            const float4 aa = *(const float4*)&Ts[r * DIM + k4 * 4];
            acc[r] += dot4(aa, w);
        }
    }
    const float bo = B5[o];
#pragma unroll
    for (int r = 0; r < 32; ++r)
        out[(size_t)(n0 + r) * DIM + o] = acc[r] + bo;
}

// epilogue: 256 combleaf blocks + 72 combine blocks
__global__ __launch_bounds__(512) void epilogue_kernel(
    const __bf16* __restrict__ O1, const __bf16* __restrict__ Wo1b,
    const float* __restrict__ w_out, const float* __restrict__ b_out,
    const float* __restrict__ tP, const float* __restrict__ Op,
    const float* __restrict__ Osf, const float* __restrict__ Oc,
    const float* __restrict__ Ors, const float* __restrict__ Orc,
    const float* __restrict__ wleaf, const float* __restrict__ winner,
    const float* __restrict__ wroot, float* __restrict__ out)
{
    extern __shared__ __align__(16) char smem[];
    const int bid = blockIdx.x;
    const size_t WO = 256 * 256, BO = 256;
    if (bid < 256) {
        combleaf_body(bid, O1, Wo1b, b_out + BO, tP, wleaf, out, smem);
    } else if (bid < 320) {
        if (threadIdx.x < 256)
            combine_inner_body(bid - 256, Op, Osf, Oc,
                               w_out + 2 * WO, b_out + 2 * BO,
                               w_out + 3 * WO, b_out + 3 * BO,
                               w_out + 4 * WO, b_out + 4 * BO,
                               winner, out + 33554432, (float*)smem);
        else {
#pragma unroll
            for (int i = 0; i < 6; ++i) __syncthreads();
        }
    } else {
        if (threadIdx.x < 256)
            combine_root_body(bid - 320, Ors, Orc, w_out + 5 * WO, b_out + 5 * BO,
                              wroot, out + 33554432 + 524288, (float*)smem);
        else
            __syncthreads();
    }
}

// ---------------------------------------------------------------------------
extern "C" void kernel_launch(void* const* d_in, const int* in_sizes, int n_in,
                              void* d_out, int out_size, void* d_ws, size_t ws_size,
                              hipStream_t stream)
{
    const float* leaf   = (const float*)d_in[0];
    const float* inner  = (const float*)d_in[1];
    const float* root   = (const float*)d_in[2];
    const float* w_in   = (const float*)d_in[3];
    const float* b_in   = (const float*)d_in[4];
    const float* w_out  = (const float*)d_in[5];
    const float* b_out  = (const float*)d_in[6];
    const float* wleaf  = (const float*)d_in[7];
    const float* winner = (const float*)d_in[8];
    const float* wroot  = (const float*)d_in[9];
    float* out = (float*)d_out;

    // ws layout
    char* ws = (char*)d_ws;
    __bf16* W1b   = (__bf16*)(ws);                    // 393216 B
    __bf16* W4kvb = (__bf16*)(ws + 393216);           // 262144 B
    __bf16* Wo1b  = (__bf16*)(ws + 655360);           // 131072 B
    __bf16* Wv0b  = (__bf16*)(ws + 786432);           // 131072 B
    __bf16* Wo0b  = (__bf16*)(ws + 917504);           // 131072 B
    __bf16* O1b   = (__bf16*)(ws + 1048576);          // 67108864 B
    float*  tP    = (float*)(ws + 68157440);          // 2097152 B
    float*  Oc    = (float*)(ws + 70254592);
    float*  Op    = (float*)(ws + 72351744);
    float*  Osf   = (float*)(ws + 74448896);
    float*  Ors   = (float*)(ws + 76546048);
    float*  Orc   = (float*)(ws + 76808192);

    // merged weight conversion (1 launch)
    cvt_all<<<512, 256, 0, stream>>>(w_in, w_out, W1b, W4kvb, Wo1b, Wv0b, Wo0b);

    // fused main: aux (4 attn + leafp) + mega2 (overlaid LDS, 3 blocks/CU)
    fused_main<<<8736, 256, 52224, stream>>>(
        leaf, inner, root, w_in, b_in, b_out, W1b, W4kvb, Wv0b, Wo0b,
        O1b, Oc, tP, Op, Osf, Ors, Orc);

    // merged epilogue: combleaf + combine_inner + combine_root
    epilogue_kernel<<<328, 512, 135168, stream>>>(O1b, Wo1b, w_out, b_out, tP,
                                                  Op, Osf, Oc, Ors, Orc,
                                                  wleaf, winner, wroot, out);
}

// Round 20
// 660.231 us; speedup vs baseline: 1.3985x; 1.1642x over previous
//
#include <hip/hip_runtime.h>
#include <hip/hip_bf16.h>
#include <cstdint>

// AttnLayerBU round 20: r17 (best, 681us) verbatim + two twice-verified launch
// merges (cvt_all single launch; combleaf+combines single epilogue launch).
// r18/r19's overlay/launch_bounds experiments are reverted (both regressed).

#define DIM 256
#define NH 8
#define HD 32

static constexpr float SCALE = 0.17677669529663687f; // 32^-0.5

typedef __bf16 bf16x8 __attribute__((ext_vector_type(8)));
typedef __bf16 bf16x4 __attribute__((ext_vector_type(4)));
typedef float  f32x4  __attribute__((ext_vector_type(4)));

__device__ __forceinline__ float dot4(const float4 a, const float4 b) {
    return a.x * b.x + a.y * b.y + a.z * b.z + a.w * b.w;
}

// ---------------------------------------------------------------------------
// merged weight converter: 5 ranges in one launch (verified r18/r19)
// ---------------------------------------------------------------------------
__device__ __forceinline__ void cvt_range(const float* __restrict__ s,
                                          __bf16* __restrict__ d, int lb, int n) {
    int i = (lb * 256 + (int)threadIdx.x) * 4;
    if (i < n) {
        float4 v = *(const float4*)(s + i);
        d[i + 0] = (__bf16)v.x; d[i + 1] = (__bf16)v.y;
        d[i + 2] = (__bf16)v.z; d[i + 3] = (__bf16)v.w;
    }
}

__global__ __launch_bounds__(256) void cvt_all(
    const float* __restrict__ w_in, const float* __restrict__ w_out,
    __bf16* __restrict__ W1b, __bf16* __restrict__ W4kvb,
    __bf16* __restrict__ Wo1b, __bf16* __restrict__ Wv0b,
    __bf16* __restrict__ Wo0b)
{
    const size_t WI = 768 * 256, WO = 256 * 256;
    const int bid = blockIdx.x;
    if (bid < 192)       cvt_range(w_in + 1 * WI, W1b, bid, 768 * 256);
    else if (bid < 320)  cvt_range(w_in + 4 * WI + 256 * 256, W4kvb, bid - 192, 512 * 256);
    else if (bid < 384)  cvt_range(w_out + 1 * WO, Wo1b, bid - 320, 256 * 256);
    else if (bid < 448)  cvt_range(w_in + 512 * 256, Wv0b, bid - 384, 256 * 256);
    else                 cvt_range(w_out, Wo0b, bid - 448, 256 * 256);
}

// ---------------------------------------------------------------------------
// mega2 body (r17 verbatim). LDS (79872 B):
//   Xs[64][264] @0 (33792)  | overlays after proj: Pw 4x[16][72]@wid*2304,
//                           |   scratch f32 @9216
//   Qs[64][72]@33792  Ks@43008  Vt@52224  K4t@61440  V4t@70656
// ---------------------------------------------------------------------------
__device__ void mega2_body(int g,
    const float* __restrict__ X, const float* __restrict__ inner,
    const __bf16* __restrict__ W1b, const float* __restrict__ Bi1,
    const __bf16* __restrict__ W4kvb, const float* __restrict__ W4q,
    const float* __restrict__ Bi4, __bf16* __restrict__ O1,
    float* __restrict__ Oc, char* __restrict__ smem)
{
    const int xcd  = g & 7;
    const int idx  = g >> 3;               // 0..1023
    const int b    = xcd * 256 + (idx >> 2);
    const int hg   = idx & 3;              // head-pair: heads 2hg, 2hg+1
    const int tid  = threadIdx.x;
    const int wid  = tid >> 6;             // 0..3
    const int lane = tid & 63;
    const int lr   = lane & 15;
    const int lk   = (lane >> 4) * 8;
    const int prow = (lane >> 4) * 4;

    __bf16* Xs  = (__bf16*)smem;                    // [64][264]
    __bf16* Pw  = (__bf16*)(smem + wid * 2304);     // overlay (post-proj)
    float* qpart = (float*)(smem + 9216);           // overlay [4][64]
    float* qv    = qpart + 256;                     // [64]
    float* psm   = qv + 64;                         // [2][64]
    float* opart = psm + 128;                       // [2][64]
    __bf16* Qs  = (__bf16*)(smem + 33792);          // [64][72]
    __bf16* Ks  = (__bf16*)(smem + 43008);
    __bf16* Vt  = (__bf16*)(smem + 52224);          // [64 d][72 tok]
    __bf16* K4t = (__bf16*)(smem + 61440);
    __bf16* V4t = (__bf16*)(smem + 70656);

    // ---- stage X tile (fp32 -> bf16) into Xs, coalesced ----
    {
        const float* xb = X + (size_t)b * 64 * DIM;
#pragma unroll
        for (int it = 0; it < 16; ++it) {
            const int e4 = it * 1024 + tid * 4;
            const f32x4 v = __builtin_nontemporal_load((const f32x4*)(xb + e4));
            bf16x4 t4;
            t4[0] = (__bf16)v[0]; t4[1] = (__bf16)v[1];
            t4[2] = (__bf16)v[2]; t4[3] = (__bf16)v[3];
            const int row = e4 >> 8, col = e4 & 255;
            *(bf16x4*)(Xs + row * 264 + col) = t4;
        }
    }
    __syncthreads();                                 // Xs ready

    // ---- load ALL A-fragments into registers (once): 4 row-groups x 8 k ----
    bf16x8 af[4][8];
#pragma unroll
    for (int tg = 0; tg < 4; ++tg)
#pragma unroll
        for (int kk = 0; kk < 8; ++kk)
            af[tg][kk] = *(const bf16x8*)(Xs + (size_t)(tg * 16 + lr) * 264 + kk * 32 + lk);

    // ---- projection: wave owns n-tiles wid*5..wid*5+4, A & B in registers ----
    {
        auto wsrc = [&](int t) -> const __bf16* {
            if (t < 12) {
                const int sec = t >> 2, sub = t & 3;
                return W1b + (size_t)(sec * 256 + hg * 64 + sub * 16) * DIM;
            }
            const int u = t - 12, sec = u >> 2, sub = u & 3;
            return W4kvb + (size_t)(sec * 256 + hg * 64 + sub * 16) * DIM;
        };
        const size_t boff = (size_t)lr * DIM + lk;
        const int t0w = wid * 5;
        bf16x8 bw[8], bn[8];
        {
            const __bf16* p = wsrc(t0w) + boff;
#pragma unroll
            for (int kk = 0; kk < 8; ++kk) bw[kk] = *(const bf16x8*)(p + kk * 32);
        }
        for (int i = 0; i < 5; ++i) {
            const int t = t0w + i;
            if (i + 1 < 5) {
                const __bf16* p = wsrc(t + 1) + boff;
#pragma unroll
                for (int kk = 0; kk < 8; ++kk) bn[kk] = *(const bf16x8*)(p + kk * 32);
            }
            f32x4 acc0 = {0.f,0.f,0.f,0.f}, acc1 = {0.f,0.f,0.f,0.f};
            f32x4 acc2 = {0.f,0.f,0.f,0.f}, acc3 = {0.f,0.f,0.f,0.f};
#pragma unroll
            for (int kk = 0; kk < 8; ++kk) {
                acc0 = __builtin_amdgcn_mfma_f32_16x16x32_bf16(af[0][kk], bw[kk], acc0, 0, 0, 0);
                acc1 = __builtin_amdgcn_mfma_f32_16x16x32_bf16(af[1][kk], bw[kk], acc1, 0, 0, 0);
                acc2 = __builtin_amdgcn_mfma_f32_16x16x32_bf16(af[2][kk], bw[kk], acc2, 0, 0, 0);
                acc3 = __builtin_amdgcn_mfma_f32_16x16x32_bf16(af[3][kk], bw[kk], acc3, 0, 0, 0);
            }
            f32x4 accT[4] = { acc0, acc1, acc2, acc3 };
            const int sub = t & 3;
            const int col = sub * 16 + lr;
            if (t < 4) {                            // Q (scaled)
                const float bias = Bi1[hg * 64 + sub * 16 + lr];
#pragma unroll
                for (int tg = 0; tg < 4; ++tg)
#pragma unroll
                    for (int r = 0; r < 4; ++r)
                        Qs[(size_t)(tg * 16 + prow + r) * 72 + col] =
                            (__bf16)((accT[tg][r] + bias) * SCALE);
            } else if (t < 8) {                     // K
                const float bias = Bi1[256 + hg * 64 + sub * 16 + lr];
#pragma unroll
                for (int tg = 0; tg < 4; ++tg)
#pragma unroll
                    for (int r = 0; r < 4; ++r)
                        Ks[(size_t)(tg * 16 + prow + r) * 72 + col] =
                            (__bf16)(accT[tg][r] + bias);
            } else if (t < 12) {                    // V -> [d][tok]
                const float bias = Bi1[512 + hg * 64 + sub * 16 + lr];
#pragma unroll
                for (int tg = 0; tg < 4; ++tg) {
                    bf16x4 pv;
#pragma unroll
                    for (int r = 0; r < 4; ++r) pv[r] = (__bf16)(accT[tg][r] + bias);
                    *(bf16x4*)(Vt + (size_t)col * 72 + tg * 16 + prow) = pv;
                }
            } else if (t < 16) {                    // K4 -> [d][tok]
                const float bias = Bi4[256 + hg * 64 + sub * 16 + lr];
#pragma unroll
                for (int tg = 0; tg < 4; ++tg) {
                    bf16x4 pv;
#pragma unroll
                    for (int r = 0; r < 4; ++r) pv[r] = (__bf16)(accT[tg][r] + bias);
                    *(bf16x4*)(K4t + (size_t)col * 72 + tg * 16 + prow) = pv;
                }
            } else {                                // V4 -> [d][tok]
                const float bias = Bi4[512 + hg * 64 + sub * 16 + lr];
#pragma unroll
                for (int tg = 0; tg < 4; ++tg) {
                    bf16x4 pv;
#pragma unroll
                    for (int r = 0; r < 4; ++r) pv[r] = (__bf16)(accT[tg][r] + bias);
                    *(bf16x4*)(V4t + (size_t)col * 72 + tg * 16 + prow) = pv;
                }
            }
#pragma unroll
            for (int kk = 0; kk < 8; ++kk) bw[kk] = bn[kk];
        }
    }
    __syncthreads();                                 // proj done, Xs dead

    // ---- inner_c q-projection partials (into Xs overlay) ----
    {
        const int o = tid & 63, part = tid >> 6;
        const float4* wr = (const float4*)(W4q + (size_t)(hg * 64 + o) * DIM + part * 64);
        const float4* xr = (const float4*)(inner + (size_t)b * DIM + part * 64);
        float accq = 0.f;
#pragma unroll
        for (int k = 0; k < 16; ++k) accq += dot4(xr[k], wr[k]);
        qpart[part * 64 + o] = accq;
    }
    __syncthreads();

    if (tid < 64)
        qv[tid] = (qpart[tid] + qpart[64 + tid] + qpart[128 + tid] + qpart[192 + tid]
                   + Bi4[hg * 64 + tid]) * SCALE;

    // ---- leaf_s attention: wave = (head hh, q-half qh) ----
    const int hh = wid >> 1;
    const int qh = wid & 1;
    f32x4 s[2][4];
    {
        bf16x8 kb[4];
#pragma unroll
        for (int kt = 0; kt < 4; ++kt)
            kb[kt] = *(const bf16x8*)(Ks + (size_t)(kt * 16 + lr) * 72 + hh * 32 + lk);
#pragma unroll
        for (int q2 = 0; q2 < 2; ++q2) {
            const int qt = qh * 2 + q2;
            const bf16x8 qa = *(const bf16x8*)(Qs + (size_t)(qt * 16 + lr) * 72 + hh * 32 + lk);
#pragma unroll
            for (int kt = 0; kt < 4; ++kt) {
                f32x4 z = {0.f, 0.f, 0.f, 0.f};
                s[q2][kt] = __builtin_amdgcn_mfma_f32_16x16x32_bf16(qa, kb[kt], z, 0, 0, 0);
            }
        }
    }
#pragma unroll
    for (int q2 = 0; q2 < 2; ++q2) {
#pragma unroll
        for (int r = 0; r < 4; ++r) {
            float m = fmaxf(fmaxf(s[q2][0][r], s[q2][1][r]), fmaxf(s[q2][2][r], s[q2][3][r]));
#pragma unroll
            for (int off = 1; off < 16; off <<= 1) m = fmaxf(m, __shfl_xor(m, off));
            const float p0 = __expf(s[q2][0][r] - m), p1 = __expf(s[q2][1][r] - m);
            const float p2 = __expf(s[q2][2][r] - m), p3 = __expf(s[q2][3][r] - m);
            float t = p0 + p1 + p2 + p3;
#pragma unroll
            for (int off = 1; off < 16; off <<= 1) t += __shfl_xor(t, off);
            const float inv = 1.0f / t;
            s[q2][0][r] = p0 * inv; s[q2][1][r] = p1 * inv;
            s[q2][2][r] = p2 * inv; s[q2][3][r] = p3 * inv;
        }
    }
    {
        bf16x8 vb[2][2];
#pragma unroll
        for (int dt = 0; dt < 2; ++dt)
#pragma unroll
            for (int ks = 0; ks < 2; ++ks)
                vb[dt][ks] = *(const bf16x8*)(Vt + (size_t)(hh * 32 + dt * 16 + lr) * 72 + ks * 32 + lk);
#pragma unroll
        for (int q2 = 0; q2 < 2; ++q2) {
            const int qt = qh * 2 + q2;
#pragma unroll
            for (int kt = 0; kt < 4; ++kt)
#pragma unroll
                for (int r = 0; r < 4; ++r)
                    Pw[(size_t)(prow + r) * 72 + kt * 16 + lr] = (__bf16)s[q2][kt][r];
            bf16x8 pa[2];
#pragma unroll
            for (int ks = 0; ks < 2; ++ks)
                pa[ks] = *(const bf16x8*)(Pw + (size_t)lr * 72 + ks * 32 + lk);
#pragma unroll
            for (int dt = 0; dt < 2; ++dt) {
                f32x4 o = {0.f, 0.f, 0.f, 0.f};
#pragma unroll
                for (int ks = 0; ks < 2; ++ks)
                    o = __builtin_amdgcn_mfma_f32_16x16x32_bf16(pa[ks], vb[dt][ks], o, 0, 0, 0);
                const int colO = (hg * 2 + hh) * 32 + dt * 16 + lr;
#pragma unroll
                for (int r = 0; r < 4; ++r)
                    __builtin_nontemporal_store((__bf16)o[r],
                        &O1[((size_t)b * 64 + qt * 16 + prow + r) * DIM + colO]);
            }
        }
    }
    __syncthreads();

    if (wid < 2) {
        const int j = lane;
        float sv = 0.f;
#pragma unroll
        for (int d = 0; d < 32; ++d)
            sv += qv[wid * 32 + d] * (float)K4t[(size_t)(wid * 32 + d) * 72 + j];
        float m = sv;
#pragma unroll
        for (int off = 1; off < 64; off <<= 1) m = fmaxf(m, __shfl_xor(m, off));
        const float p = __expf(sv - m);
        float t = p;
#pragma unroll
        for (int off = 1; off < 64; off <<= 1) t += __shfl_xor(t, off);
        psm[wid * 64 + j] = p / t;
    }
    __syncthreads();

    if (tid < 128) {
        const int o = tid & 63, hf = tid >> 6;
        const int ho = o >> 5;
        float acc2 = 0.f;
#pragma unroll
        for (int j = 0; j < 32; ++j)
            acc2 += psm[ho * 64 + hf * 32 + j] * (float)V4t[(size_t)o * 72 + hf * 32 + j];
        opart[hf * 64 + o] = acc2;
    }
    __syncthreads();
    if (tid < 64)
        Oc[(size_t)b * DIM + hg * 64 + tid] = opart[tid] + opart[64 + tid];
}

// ---------------------------------------------------------------------------
// leafp MFMA 2-stage (r12 verbatim)
// ---------------------------------------------------------------------------
__device__ void leafp_mfma_body(int bid, const float* __restrict__ inner,
    const __bf16* __restrict__ Wv0b, const __bf16* __restrict__ Wo0b,
    const float* __restrict__ b_in0, const float* __restrict__ b_out0,
    float* __restrict__ tP, char* __restrict__ smem)
{
    __bf16* tV = (__bf16*)smem;             // [64][264]
    __bf16* Bs = (__bf16*)(smem + 33792);   // [2][16][264]
    const int tid  = threadIdx.x;
    const int wid  = tid >> 6;
    const int lane = tid & 63;
    const int lr   = lane & 15;
    const int lk   = (lane >> 4) * 8;
    const int prow = (lane >> 4) * 4;
    const int tok0 = wid * 16 + prow;
    const int srow = tid >> 5;
    const int scol = (tid & 31) * 8;

    bf16x8 a[8];
    {
        const float* xrow = inner + ((size_t)bid * 64 + wid * 16 + lr) * DIM + lk;
#pragma unroll
        for (int k = 0; k < 8; ++k) {
            float4 v0 = *(const float4*)(xrow + k * 32);
            float4 v1 = *(const float4*)(xrow + k * 32 + 4);
            bf16x8 t;
            t[0] = (__bf16)v0.x; t[1] = (__bf16)v0.y; t[2] = (__bf16)v0.z; t[3] = (__bf16)v0.w;
            t[4] = (__bf16)v1.x; t[5] = (__bf16)v1.y; t[6] = (__bf16)v1.z; t[7] = (__bf16)v1.w;
            a[k] = t;
        }
    }

    {
        bf16x8 g0 = *(const bf16x8*)(Wv0b + (size_t)srow * DIM + scol);
        bf16x8 g1 = *(const bf16x8*)(Wv0b + (size_t)(8 + srow) * DIM + scol);
        *(bf16x8*)(Bs + srow * 264 + scol) = g0;
        *(bf16x8*)(Bs + (8 + srow) * 264 + scol) = g1;
    }
    __syncthreads();
    for (int t = 0; t < 16; ++t) {
        const int cur = t & 1;
        const __bf16* Bc = Bs + cur * 4224;
        bf16x8 g0, g1;
        if (t + 1 < 16) {
            const __bf16* p = Wv0b + (size_t)((t + 1) * 16) * DIM;
            g0 = *(const bf16x8*)(p + (size_t)srow * DIM + scol);
            g1 = *(const bf16x8*)(p + (size_t)(8 + srow) * DIM + scol);
        }
        f32x4 acc = {0.f, 0.f, 0.f, 0.f};
#pragma unroll
        for (int k = 0; k < 8; ++k)
            acc = __builtin_amdgcn_mfma_f32_16x16x32_bf16(
                a[k], *(const bf16x8*)(Bc + lr * 264 + k * 32 + lk), acc, 0, 0, 0);
        const float bias = b_in0[512 + t * 16 + lr];
#pragma unroll
        for (int r = 0; r < 4; ++r)
            tV[(size_t)(tok0 + r) * 264 + t * 16 + lr] = (__bf16)(acc[r] + bias);
        if (t + 1 < 16) {
            __bf16* Bn = Bs + (cur ^ 1) * 4224;
            *(bf16x8*)(Bn + srow * 264 + scol) = g0;
            *(bf16x8*)(Bn + (8 + srow) * 264 + scol) = g1;
        }
        __syncthreads();
    }

    bf16x8 a2[8];
#pragma unroll
    for (int k = 0; k < 8; ++k)
        a2[k] = *(const bf16x8*)(tV + (size_t)(wid * 16 + lr) * 264 + k * 32 + lk);
    {
        bf16x8 g0 = *(const bf16x8*)(Wo0b + (size_t)srow * DIM + scol);
        bf16x8 g1 = *(const bf16x8*)(Wo0b + (size_t)(8 + srow) * DIM + scol);
        *(bf16x8*)(Bs + srow * 264 + scol) = g0;
        *(bf16x8*)(Bs + (8 + srow) * 264 + scol) = g1;
    }
    __syncthreads();
    for (int t = 0; t < 16; ++t) {
        const int cur = t & 1;
        const __bf16* Bc = Bs + cur * 4224;
        bf16x8 g0, g1;
        if (t + 1 < 16) {
            const __bf16* p = Wo0b + (size_t)((t + 1) * 16) * DIM;
            g0 = *(const bf16x8*)(p + (size_t)srow * DIM + scol);
            g1 = *(const bf16x8*)(p + (size_t)(8 + srow) * DIM + scol);
        }
        f32x4 acc = {0.f, 0.f, 0.f, 0.f};
#pragma unroll
        for (int k = 0; k < 8; ++k)
            acc = __builtin_amdgcn_mfma_f32_16x16x32_bf16(
                a2[k], *(const bf16x8*)(Bc + lr * 264 + k * 32 + lk), acc, 0, 0, 0);
        const float bo = b_out0[t * 16 + lr];
#pragma unroll
        for (int r = 0; r < 4; ++r)
            tP[((size_t)bid * 64 + wid * 16 + prow + r) * DIM + t * 16 + lr] = acc[r] + bo;
        if (t + 1 < 16) {
            __bf16* Bn = Bs + (cur ^ 1) * 4224;
            *(bf16x8*)(Bn + srow * 264 + scol) = g0;
            *(bf16x8*)(Bn + (8 + srow) * 264 + scol) = g1;
        }
        __syncthreads();
    }
}

// ---------------------------------------------------------------------------
// fp32 fused attention body (r12/r17 verbatim)
// ---------------------------------------------------------------------------
template <int LQ, int LK, int RQ>
__device__ void attn_body(int bx, const float* __restrict__ Xq,
                          const float* __restrict__ Xkv,
                          const float* __restrict__ Wi, const float* __restrict__ Bi,
                          float* __restrict__ O, float* __restrict__ sm)
{
    const int b   = bx >> 3;
    const int h   = bx & 7;
    const int tid = threadIdx.x;

    float* KsP = sm;                    // [LK][33]
    float* VsP = KsP + LK * 33;         // [LK][33]
    float* QsP = VsP + LK * 33;         // [LQ][33]
    float* SP  = QsP + LQ * 33;         // [RQ][LK+1]

    const float* xq  = Xq  + (size_t)b * LQ * DIM;
    const float* xkv = Xkv + (size_t)b * LK * DIM;

    {
        const int col   = tid & 63;
        const int which = col >> 5;
        const int d     = col & 31;
        const int row   = DIM + which * DIM + h * HD + d;
        const float4* wr = (const float4*)(Wi + (size_t)row * DIM);
        const float bias = Bi[row];
        constexpr int TT = LK / 4;
        float acc[TT];
#pragma unroll
        for (int i = 0; i < TT; ++i) acc[i] = 0.f;
        const int t0 = tid >> 6;
        for (int k4 = 0; k4 < DIM / 4; ++k4) {
            const float4 w = wr[k4];
#pragma unroll
            for (int i = 0; i < TT; ++i) {
                const int t = t0 + 4 * i;
                const float4 aa = ((const float4*)(xkv + (size_t)t * DIM))[k4];
                acc[i] += dot4(aa, w);
            }
        }
#pragma unroll
        for (int i = 0; i < TT; ++i) {
            const int t = t0 + 4 * i;
            if (which == 0) KsP[t * 33 + d] = acc[i] + bias;
            else            VsP[t * 33 + d] = acc[i] + bias;
        }
    }
    {
        constexpr int TGQ = (LQ >= 8) ? 8 : LQ;
        constexpr int TT  = LQ / TGQ;
        if (tid < 32 * TGQ) {
            const int d   = tid & 31;
            const int row = h * HD + d;
            const float4* wr = (const float4*)(Wi + (size_t)row * DIM);
            const float bias = Bi[row];
            float acc[TT];
#pragma unroll
            for (int i = 0; i < TT; ++i) acc[i] = 0.f;
            const int t0 = tid >> 5;
            for (int k4 = 0; k4 < DIM / 4; ++k4) {
                const float4 w = wr[k4];
#pragma unroll
                for (int i = 0; i < TT; ++i) {
                    const int t = t0 + TGQ * i;
                    const float4 aa = ((const float4*)(xq + (size_t)t * DIM))[k4];
                    acc[i] += dot4(aa, w);
                }
            }
#pragma unroll
            for (int i = 0; i < TT; ++i) {
                const int t = t0 + TGQ * i;
                QsP[t * 33 + d] = (acc[i] + bias) * SCALE;
            }
        }
    }
    __syncthreads();

    for (int q0 = 0; q0 < LQ; q0 += RQ) {
        for (int idx = tid; idx < RQ * LK; idx += 256) {
            const int r = idx / LK;
            const int j = idx - r * LK;
            float acc = 0.f;
#pragma unroll
            for (int d = 0; d < HD; ++d)
                acc += QsP[(q0 + r) * 33 + d] * KsP[j * 33 + d];
            SP[r * (LK + 1) + j] = acc;
        }
        __syncthreads();
        if (tid < RQ * 8) {
            const int r   = tid >> 3;
            const int sub = tid & 7;
            float m = -1e30f;
            for (int j = sub; j < LK; j += 8) m = fmaxf(m, SP[r * (LK + 1) + j]);
#pragma unroll
            for (int off = 4; off; off >>= 1) m = fmaxf(m, __shfl_xor(m, off, 8));
            float sum = 0.f;
            for (int j = sub; j < LK; j += 8) {
                const float p = __expf(SP[r * (LK + 1) + j] - m);
                SP[r * (LK + 1) + j] = p;
                sum += p;
            }
#pragma unroll
            for (int off = 4; off; off >>= 1) sum += __shfl_xor(sum, off, 8);
            const float inv = 1.0f / sum;
            for (int j = sub; j < LK; j += 8) SP[r * (LK + 1) + j] *= inv;
        }
        __syncthreads();
        for (int idx = tid; idx < RQ * HD; idx += 256) {
            const int r = idx >> 5;
            const int d = idx & 31;
            float acc = 0.f;
            for (int j = 0; j < LK; ++j)
                acc += SP[r * (LK + 1) + j] * VsP[j * 33 + d];
            O[((size_t)(b * LQ + q0 + r)) * DIM + h * HD + d] = acc;
        }
        __syncthreads();
    }
}

// ---------------------------------------------------------------------------
// fused_main (r17 verbatim: 79872 B dyn LDS, launch_bounds(256,2))
// ---------------------------------------------------------------------------
__global__ __launch_bounds__(256, 2) void fused_main(
    const float* __restrict__ leaf, const float* __restrict__ inner,
    const float* __restrict__ root,
    const float* __restrict__ w_in, const float* __restrict__ b_in,
    const float* __restrict__ b_out,
    const __bf16* __restrict__ W1b, const __bf16* __restrict__ W4kvb,
    const __bf16* __restrict__ Wv0b, const __bf16* __restrict__ Wo0b,
    __bf16* __restrict__ O1, float* __restrict__ Oc, float* __restrict__ tP,
    float* __restrict__ Op, float* __restrict__ Osf,
    float* __restrict__ Ors, float* __restrict__ Orc)
{
    extern __shared__ __align__(16) char smem[];
    const int bid = blockIdx.x;
    const size_t WI = 768 * 256, BI = 768;
    if (bid < 128)
        attn_body<128, 128, 16>(bid, inner, inner, w_in + 3 * WI, b_in + 3 * BI,
                                Osf, (float*)smem);
    else if (bid < 256)
        attn_body<128, 16, 32>(bid - 128, inner, root, w_in + 2 * WI, b_in + 2 * BI,
                               Op, (float*)smem);
    else if (bid < 384)
        attn_body<16, 128, 16>(bid - 256, root, inner, w_in + 5 * WI, b_in + 5 * BI,
                               Orc, (float*)smem);
    else if (bid < 512)
        attn_body<16, 16, 16>(bid - 384, root, root, w_in + 5 * WI, b_in + 5 * BI,
                              Ors, (float*)smem);
    else if (bid < 544)
        leafp_mfma_body(bid - 512, inner, Wv0b, Wo0b, b_in, b_out, tP, smem);
    else
        mega2_body(bid - 544, leaf, inner, W1b, b_in + 1 * BI, W4kvb,
                   w_in + 4 * WI, b_in + 4 * BI, O1, Oc, smem);
}

// ---------------------------------------------------------------------------
// combleaf body (r17 verbatim) + combines, merged epilogue (verified r18/r19)
// ---------------------------------------------------------------------------
__device__ void combleaf_body(int bid, const __bf16* __restrict__ O1,
    const __bf16* __restrict__ Wo1, const float* __restrict__ Bo1,
    const float* __restrict__ tP, const float* __restrict__ wleaf,
    float* __restrict__ out, char* __restrict__ smem)
{
    __bf16* Ws = (__bf16*)smem;             // [256][264]
    const int tid  = threadIdx.x;
    const int wid  = tid >> 6;              // 0..7 (wave = one leaf tile)
    const int lane = tid & 63;
    const int lr   = lane & 15;
    const int lk   = (lane >> 4) * 8;
    const int prow = (lane >> 4) * 4;

    bf16x8 a[4][8];
#pragma unroll
    for (int tg = 0; tg < 4; ++tg) {
        const __bf16* ar = O1 + ((size_t)bid * 512 + wid * 64 + tg * 16 + lr) * DIM + lk;
#pragma unroll
        for (int k = 0; k < 8; ++k) a[tg][k] = *(const bf16x8*)(ar + k * 32);
    }
    {
        const int row = tid >> 1, hf = tid & 1;
        const __bf16* p = Wo1 + (size_t)row * DIM + hf * 128;
        __bf16* dst = Ws + (size_t)row * 264 + hf * 128;
#pragma unroll
        for (int q = 0; q < 16; ++q)
            *(bf16x8*)(dst + q * 8) = *(const bf16x8*)(p + q * 8);
    }
    __syncthreads();

    const float e0 = __expf(wleaf[0]), e1 = __expf(wleaf[1]);
    const float wl0 = e0 / (e0 + e1), wl1 = e1 / (e0 + e1);
    const int   tile = bid * 8 + wid;
    const size_t rb  = (size_t)bid * 512 + wid * 64;

    for (int nt = 0; nt < 16; ++nt) {
        bf16x8 bw[8];
#pragma unroll
        for (int k = 0; k < 8; ++k)
            bw[k] = *(const bf16x8*)(Ws + (size_t)(nt * 16 + lr) * 264 + k * 32 + lk);
        f32x4 acc0 = {0.f,0.f,0.f,0.f}, acc1 = {0.f,0.f,0.f,0.f};
        f32x4 acc2 = {0.f,0.f,0.f,0.f}, acc3 = {0.f,0.f,0.f,0.f};
#pragma unroll
        for (int k = 0; k < 8; ++k) {
            acc0 = __builtin_amdgcn_mfma_f32_16x16x32_bf16(a[0][k], bw[k], acc0, 0, 0, 0);
            acc1 = __builtin_amdgcn_mfma_f32_16x16x32_bf16(a[1][k], bw[k], acc1, 0, 0, 0);
            acc2 = __builtin_amdgcn_mfma_f32_16x16x32_bf16(a[2][k], bw[k], acc2, 0, 0, 0);
            acc3 = __builtin_amdgcn_mfma_f32_16x16x32_bf16(a[3][k], bw[k], acc3, 0, 0, 0);
        }
        f32x4 accT[4] = { acc0, acc1, acc2, acc3 };
        const int   o  = nt * 16 + lr;
        const float bo = Bo1[o];
        const float tv = tP[(size_t)tile * DIM + o];
#pragma unroll
        for (int tg = 0; tg < 4; ++tg)
#pragma unroll
            for (int r = 0; r < 4; ++r)
                out[(rb + tg * 16 + prow + r) * DIM + o] =
                    wl0 * tv + wl1 * (accT[tg][r] + bo);
    }
}

__device__ void combine_inner_body(int vb, const float* __restrict__ Op,
    const float* __restrict__ Osf, const float* __restrict__ Oc,
    const float* __restrict__ W2, const float* __restrict__ B2,
    const float* __restrict__ W3, const float* __restrict__ B3,
    const float* __restrict__ W4, const float* __restrict__ B4,
    const float* __restrict__ winner, float* __restrict__ out, float* __restrict__ Ts)
{
    const int n0 = vb * 32;
    const int o  = threadIdx.x & 255;
    const float e0 = __expf(winner[0]), e1 = __expf(winner[1]), e2 = __expf(winner[2]);
    const float inv = 1.f / (e0 + e1 + e2);
    const float wt0 = e0 * inv, wt1 = e1 * inv, wt2 = e2 * inv;

    float acc[32];
#pragma unroll
    for (int r = 0; r < 32; ++r) acc[r] = 0.f;
    const float biasacc = wt0 * B2[o] + wt1 * B3[o] + wt2 * B4[o];

#pragma unroll
    for (int term = 0; term < 3; ++term) {
        const float* Ob = (term == 0) ? Op : (term == 1) ? Osf : Oc;
        const float* Wb = (term == 0) ? W2 : (term == 1) ? W3 : W4;
        const float wt  = (term == 0) ? wt0 : (term == 1) ? wt1 : wt2;
        __syncthreads();
        for (int idx = threadIdx.x; idx < 32 * DIM; idx += 256)
            Ts[idx] = Ob[(size_t)n0 * DIM + idx];
        __syncthreads();
        const float4* wr = (const float4*)(Wb + (size_t)o * DIM);
        for (int k4 = 0; k4 < DIM / 4; ++k4) {
            float4 w = wr[k4];
            w.x *= wt; w.y *= wt; w.z *= wt; w.w *= wt;
#pragma unroll
            for (int r = 0; r < 32; ++r) {
                const float4 aa = *(const float4*)&Ts[r * DIM + k4 * 4];
                acc[r] += dot4(aa, w);
            }
        }
    }
#pragma unroll
    for (int r = 0; r < 32; ++r)
        out[(size_t)(n0 + r) * DIM + o] = acc[r] + biasacc;
}

__device__ void combine_root_body(int vb, const float* __restrict__ Ors,
    const float* __restrict__ Orc, const float* __restrict__ W5,
    const float* __restrict__ B5, const float* __restrict__ wroot,
    float* __restrict__ out, float* __restrict__ Ts)
{
    const int n0 = vb * 32;
    const int o  = threadIdx.x & 255;
    const float e0 = __expf(wroot[0]), e1 = __expf(wroot[1]);
    const float w0 = e0 / (e0 + e1), w1 = e1 / (e0 + e1);
    for (int idx = threadIdx.x; idx < 32 * DIM; idx += 256)
        Ts[idx] = w0 * Ors[(size_t)n0 * DIM + idx] + w1 * Orc[(size_t)n0 * DIM + idx];
    __syncthreads();
    float acc[32];
#pragma unroll
    for (int r = 0; r < 32; ++r) acc[r] = 0.f;
    const float4* wr = (const float4*)(W5 + (size_t)o * DIM);
    for (int k4 = 0; k4 < DIM / 4; ++k4) {
        const float4 w = wr[k4];
#pragma unroll
        for (int r = 0; r < 32; ++r) {
            const float4 aa = *(const float4*)&Ts[r * DIM + k4 * 4];
            acc[r] += dot4(aa, w);
        }
    }
    const float bo = B5[o];
#pragma unroll
    for (int r = 0; r < 32; ++r)
        out[(size_t)(n0 + r) * DIM + o] = acc[r] + bo;
}

__global__ __launch_bounds__(512) void epilogue_kernel(
    const __bf16* __restrict__ O1, const __bf16* __restrict__ Wo1b,
    const float* __restrict__ w_out, const float* __restrict__ b_out,
    const float* __restrict__ tP, const float* __restrict__ Op,
    const float* __restrict__ Osf, const float* __restrict__ Oc,
    const float* __restrict__ Ors, const float* __restrict__ Orc,
    const float* __restrict__ wleaf, const float* __restrict__ winner,
    const float* __restrict__ wroot, float* __restrict__ out)
{
    extern __shared__ __align__(16) char smem[];
    const int bid = blockIdx.x;
    const size_t WO = 256 * 256, BO = 256;
    if (bid < 256) {
        combleaf_body(bid, O1, Wo1b, b_out + BO, tP, wleaf, out, smem);
    } else if (bid < 320) {
        if (threadIdx.x < 256)
            combine_inner_body(bid - 256, Op, Osf, Oc,
                               w_out + 2 * WO, b_out + 2 * BO,
                               w_out + 3 * WO, b_out + 3 * BO,
                               w_out + 4 * WO, b_out + 4 * BO,
                               winner, out + 33554432, (float*)smem);
        else {
#pragma unroll
            for (int i = 0; i < 6; ++i) __syncthreads();
        }
    } else {
        if (threadIdx.x < 256)
            combine_root_body(bid - 320, Ors, Orc, w_out + 5 * WO, b_out + 5 * BO,
                              wroot, out + 33554432 + 524288, (float*)smem);
        else
            __syncthreads();
    }
}

// ---------------------------------------------------------------------------
extern "C" void kernel_launch(void* const* d_in, const int* in_sizes, int n_in,
                              void* d_out, int out_size, void* d_ws, size_t ws_size,
                              hipStream_t stream)
{
    const float* leaf   = (const float*)d_in[0];
    const float* inner  = (const float*)d_in[1];
    const float* root   = (const float*)d_in[2];
    const float* w_in   = (const float*)d_in[3];
    const float* b_in   = (const float*)d_in[4];
    const float* w_out  = (const float*)d_in[5];
    const float* b_out  = (const float*)d_in[6];
    const float* wleaf  = (const float*)d_in[7];
    const float* winner = (const float*)d_in[8];
    const float* wroot  = (const float*)d_in[9];
    float* out = (float*)d_out;

    // ws layout
    char* ws = (char*)d_ws;
    __bf16* W1b   = (__bf16*)(ws);                    // 393216 B
    __bf16* W4kvb = (__bf16*)(ws + 393216);           // 262144 B
    __bf16* Wo1b  = (__bf16*)(ws + 655360);           // 131072 B
    __bf16* Wv0b  = (__bf16*)(ws + 786432);           // 131072 B
    __bf16* Wo0b  = (__bf16*)(ws + 917504);           // 131072 B
    __bf16* O1b   = (__bf16*)(ws + 1048576);          // 67108864 B
    float*  tP    = (float*)(ws + 68157440);          // 2097152 B
    float*  Oc    = (float*)(ws + 70254592);
    float*  Op    = (float*)(ws + 72351744);
    float*  Osf   = (float*)(ws + 74448896);
    float*  Ors   = (float*)(ws + 76546048);
    float*  Orc   = (float*)(ws + 76808192);

    // merged weight conversion (1 launch; verified r18/r19)
    cvt_all<<<512, 256, 0, stream>>>(w_in, w_out, W1b, W4kvb, Wo1b, Wv0b, Wo0b);

    // fused main: aux (4 attn + leafp) + mega2 (r17 A-in-regs projection)
    fused_main<<<8736, 256, 79872, stream>>>(
        leaf, inner, root, w_in, b_in, b_out, W1b, W4kvb, Wv0b, Wo0b,
        O1b, Oc, tP, Op, Osf, Ors, Orc);

    // merged epilogue: combleaf (Wo1-resident, A-in-regs) + combines
    epilogue_kernel<<<328, 512, 135168, stream>>>(O1b, Wo1b, w_out, b_out, tP,
                                                  Op, Osf, Oc, Ors, Orc,
                                                  wleaf, winner, wroot, out);
}